// Round 1
// baseline (474.536 us; speedup 1.0000x reference)
//
#include <hip/hip_runtime.h>
#include <hip/hip_bf16.h>

typedef __attribute__((ext_vector_type(4))) float f32x4;
typedef __attribute__((ext_vector_type(8))) short bf16x8;

#define MFMA16(a, b, c) __builtin_amdgcn_mfma_f32_16x16x32_bf16(a, b, c, 0, 0, 0)

constexpr int BATCH = 4;
constexpr int SEQ   = 2048;
constexpr int DIM   = 1024;

__device__ __forceinline__ ushort f2b(float f) {
  __hip_bfloat16 h = __float2bfloat16(f);
  union { __hip_bfloat16 h; ushort u; } cv; cv.h = h; return cv.u;
}

// ---------------- fp32 -> bf16 convert (vectorized) ----------------
__global__ __launch_bounds__(256) void cvt_f32_to_bf16(const float* __restrict__ in,
                                                       ushort* __restrict__ out, int n4) {
  int i = blockIdx.x * 256 + threadIdx.x;
  if (i < n4) {
    float4 v = reinterpret_cast<const float4*>(in)[i];
    ushort4 o;
    o.x = f2b(v.x); o.y = f2b(v.y); o.z = f2b(v.z); o.w = f2b(v.w);
    reinterpret_cast<ushort4*>(out)[i] = o;
  }
}

// ---------------- async global->LDS helper ----------------
__device__ __forceinline__ void gload_lds16(const void* g, void* l) {
  __builtin_amdgcn_global_load_lds(
      (const __attribute__((address_space(1))) unsigned int*)g,
      (__attribute__((address_space(3))) unsigned int*)l, 16, 0, 0);
}

// ---------------- QKV projection GEMM ----------------
// C[m][n] = sum_k X[m][k] * W[n][k] + bias[n], all bf16 in, bf16 out, f32 acc.
// 128x128 tile, BK=32, 4 waves, double-buffered global_load_lds staging.
__global__ __launch_bounds__(256) void qkv_gemm(
    const ushort* __restrict__ X,   // [8192][1024] bf16
    const ushort* __restrict__ W3,  // [3][1024][1024] bf16
    const float* __restrict__ bq, const float* __restrict__ bk, const float* __restrict__ bv,
    ushort* __restrict__ Qo, ushort* __restrict__ Ko, ushort* __restrict__ Vo)
{
  constexpr int K = DIM, N = DIM;
  __shared__ ushort As[2][128 * 32];
  __shared__ ushort Bs[2][128 * 32];
  const int which = blockIdx.z;
  const ushort* Wm = W3 + (size_t)which * N * K;
  const float* bias = which == 0 ? bq : (which == 1 ? bk : bv);
  ushort* C = which == 0 ? Qo : (which == 1 ? Ko : Vo);
  const int m0 = blockIdx.y * 128;
  const int n0 = blockIdx.x * 128;
  const int t = threadIdx.x;
  const int lane = t & 63;
  const int w = t >> 6;
  const int wm = w >> 1, wn = w & 1;

  f32x4 acc[4][4];
#pragma unroll
  for (int mi = 0; mi < 4; ++mi)
#pragma unroll
    for (int ni = 0; ni < 4; ++ni) acc[mi][ni] = 0.f;

  auto stage = [&](int buf, int kt) {
#pragma unroll
    for (int i = 0; i < 2; ++i) {
      int p = i * 256 + t;
      int row = p >> 2, ch = p & 3;
      const char* srcA = (const char*)X  + (size_t)(m0 + row) * (K * 2) + kt * 64 + ch * 16;
      const char* srcB = (const char*)Wm + (size_t)(n0 + row) * (K * 2) + kt * 64 + ch * 16;
      char* dstA = (char*)&As[buf][0] + (size_t)(i * 256 + (t & ~63)) * 16;
      char* dstB = (char*)&Bs[buf][0] + (size_t)(i * 256 + (t & ~63)) * 16;
      gload_lds16(srcA, dstA);
      gload_lds16(srcB, dstB);
    }
  };

  stage(0, 0);
  __syncthreads();
  int buf = 0;
  for (int kt = 0; kt < K / 32; ++kt) {
    if (kt + 1 < K / 32) stage(buf ^ 1, kt + 1);
    bf16x8 a[4], b[4];
#pragma unroll
    for (int i = 0; i < 4; ++i) {
      int rowA = wm * 64 + i * 16 + (lane & 15);
      a[i] = *(const bf16x8*)((const char*)&As[buf][0] + rowA * 64 + (lane >> 4) * 16);
      int rowB = wn * 64 + i * 16 + (lane & 15);
      b[i] = *(const bf16x8*)((const char*)&Bs[buf][0] + rowB * 64 + (lane >> 4) * 16);
    }
#pragma unroll
    for (int mi = 0; mi < 4; ++mi)
#pragma unroll
      for (int ni = 0; ni < 4; ++ni)
        acc[mi][ni] = MFMA16(a[mi], b[ni], acc[mi][ni]);
    __syncthreads();   // drains staging vmcnt + protects LDS reuse
    buf ^= 1;
  }

#pragma unroll
  for (int mi = 0; mi < 4; ++mi)
#pragma unroll
    for (int ni = 0; ni < 4; ++ni) {
      int gn = n0 + wn * 64 + ni * 16 + (lane & 15);
      float bb = bias[gn];
#pragma unroll
      for (int r = 0; r < 4; ++r) {
        int gm = m0 + wm * 64 + mi * 16 + (lane >> 4) * 4 + r;
        C[(size_t)gm * N + gn] = f2b(acc[mi][ni][r] + bb);
      }
    }
}

// ---------------- V transpose: Vt[b][d][n] = V[b][n][d] ----------------
__global__ __launch_bounds__(256) void transpose_v(const ushort* __restrict__ Vb,
                                                   ushort* __restrict__ Vt) {
  __shared__ ushort tile[32][33];
  int b  = blockIdx.z;
  int n0 = blockIdx.x * 32, d0 = blockIdx.y * 32;
  int tx = threadIdx.x, ty = threadIdx.y;  // 32 x 8
#pragma unroll
  for (int j = 0; j < 32; j += 8)
    tile[ty + j][tx] = Vb[((size_t)b * SEQ + n0 + ty + j) * DIM + d0 + tx];
  __syncthreads();
#pragma unroll
  for (int j = 0; j < 32; j += 8)
    Vt[((size_t)b * DIM + d0 + ty + j) * SEQ + n0 + tx] = tile[tx][ty + j];
}

// ---------------- fused flash attention ----------------
// 1 block = (batch, 32 q rows). 8 waves. Online softmax.
// S-phase: wave grid 2x4 over (q 2x16, kv 4x16), K read global->frag.
// PV: wave w owns d-slice [w*128, w*128+128), O^T frags in registers.
__global__ __launch_bounds__(512) void attn_fwd(
    const ushort* __restrict__ Qb, const ushort* __restrict__ Kb,
    const ushort* __restrict__ Vt, float* __restrict__ Out)
{
  constexpr int D = DIM, NN = SEQ, QB = 32, KVB = 64;
  __shared__ ushort Qs[QB * D];          // XOR-swizzled, 64 KB
  __shared__ float  Ss[QB][KVB + 1];     // padded
  __shared__ ushort Ps[QB * KVB];        // XOR-swizzled
  __shared__ float  mrow[QB], lrow[QB], arow[QB];

  const int t = threadIdx.x;
  const int lane = t & 63;
  const int w = t >> 6;
  const int q0 = blockIdx.x * QB;
  const int b  = blockIdx.y;
  const ushort* Qg = Qb + ((size_t)b * NN + q0) * D;
  const ushort* Kg = Kb + (size_t)b * NN * D;
  const ushort* Vg = Vt + (size_t)b * D * NN;

  // stage Q tile into LDS with byte ^= ((row&7)<<4) swizzle
#pragma unroll
  for (int i = 0; i < 8; ++i) {
    int p = (i * 512 + t) * 16;
    int row = p >> 11;           // 2048 B per row
    int col = p & 2047;
    uint4 v = *(const uint4*)((const char*)Qg + (size_t)row * 2048 + col);
    *(uint4*)((char*)Qs + row * 2048 + (col ^ ((row & 7) << 4))) = v;
  }
  if (t < QB) { mrow[t] = -__builtin_inff(); lrow[t] = 0.f; arow[t] = 1.f; }
  __syncthreads();

  const int wm = w >> 2, wn = w & 3;
  const int d0 = w * 128;
  f32x4 o[8][2];
#pragma unroll
  for (int i = 0; i < 8; ++i) { o[i][0] = 0.f; o[i][1] = 0.f; }

  const int qrow = wm * 16 + (lane & 15);
  const char* qbase = (const char*)Qs + qrow * 2048;
  const int qx = (qrow & 7) << 4;
  const int koffB = (lane >> 4) * 16;

  for (int kt = 0; kt < NN / KVB; ++kt) {
    const int kv0 = kt * KVB;
    // ---- S = (Q K^T) / 32, wave computes one 16x16 frag over full D ----
    f32x4 s0 = 0.f, s1 = 0.f;
    const ushort* krow = Kg + (size_t)(kv0 + wn * 16 + (lane & 15)) * D + (lane >> 4) * 8;
#pragma unroll 4
    for (int dc = 0; dc < D / 64; ++dc) {
      bf16x8 a0 = *(const bf16x8*)(qbase + (((dc * 2    ) * 64 + koffB) ^ qx));
      bf16x8 a1 = *(const bf16x8*)(qbase + (((dc * 2 + 1) * 64 + koffB) ^ qx));
      bf16x8 k0 = *(const bf16x8*)(krow + (dc * 2    ) * 32);
      bf16x8 k1 = *(const bf16x8*)(krow + (dc * 2 + 1) * 32);
      s0 = MFMA16(a0, k0, s0);
      s1 = MFMA16(a1, k1, s1);
    }
    {
      f32x4 sv = (s0 + s1) * 0.03125f;
      int col = wn * 16 + (lane & 15);
      int r0 = wm * 16 + (lane >> 4) * 4;
#pragma unroll
      for (int r = 0; r < 4; ++r) Ss[r0 + r][col] = sv[r];
    }
    __syncthreads();
    // ---- online softmax: 16 threads per row ----
    {
      int row = t >> 4, c0 = t & 15;
      float s[4];
#pragma unroll
      for (int j = 0; j < 4; ++j) s[j] = Ss[row][c0 + 16 * j];
      float mx = fmaxf(fmaxf(s[0], s[1]), fmaxf(s[2], s[3]));
#pragma unroll
      for (int off = 1; off < 16; off <<= 1) mx = fmaxf(mx, __shfl_xor(mx, off));
      float mold = mrow[row];
      float mnew = fmaxf(mold, mx);
      float sum = 0.f;
      char* prow = (char*)Ps + row * 128;
      int rx = (row & 7) << 4;
#pragma unroll
      for (int j = 0; j < 4; ++j) {
        float p = __expf(s[j] - mnew);
        sum += p;
        int cb = (c0 + 16 * j) * 2;
        *(ushort*)(prow + (cb ^ rx)) = f2b(p);
      }
#pragma unroll
      for (int off = 1; off < 16; off <<= 1) sum += __shfl_xor(sum, off);
      if (c0 == 0) {
        float al = __expf(mold - mnew);
        mrow[row] = mnew;
        lrow[row] = lrow[row] * al + sum;
        arow[row] = al;
      }
    }
    __syncthreads();
    // ---- rescale O, then O^T += Vt * P ----
    {
      float a0 = arow[lane & 15];
      float a1 = arow[16 + (lane & 15)];
#pragma unroll
      for (int df = 0; df < 8; ++df) { o[df][0] *= a0; o[df][1] *= a1; }
    }
    bf16x8 pf[2][2];
#pragma unroll
    for (int ks = 0; ks < 2; ++ks)
#pragma unroll
      for (int qf = 0; qf < 2; ++qf) {
        int q = qf * 16 + (lane & 15);
        int cb = ks * 64 + (lane >> 4) * 16;
        pf[ks][qf] = *(const bf16x8*)((const char*)Ps + q * 128 + (cb ^ ((q & 7) << 4)));
      }
#pragma unroll
    for (int df = 0; df < 8; ++df) {
      const ushort* vr = Vg + (size_t)(d0 + df * 16 + (lane & 15)) * NN + kv0 + (lane >> 4) * 8;
      bf16x8 v0 = *(const bf16x8*)vr;
      bf16x8 v1 = *(const bf16x8*)(vr + 32);
      o[df][0] = MFMA16(v0, pf[0][0], o[df][0]);
      o[df][0] = MFMA16(v1, pf[1][0], o[df][0]);
      o[df][1] = MFMA16(v0, pf[0][1], o[df][1]);
      o[df][1] = MFMA16(v1, pf[1][1], o[df][1]);
    }
    // no barrier needed: next S-phase touches only Ss; softmax(t+1) is
    // barrier-protected from this PV's Ps/arow reads.
  }

  // ---- epilogue: divide by l, store fp32 ----
  float li0 = 1.f / lrow[lane & 15];
  float li1 = 1.f / lrow[16 + (lane & 15)];
  float* outp = Out + ((size_t)b * NN + q0) * D;
#pragma unroll
  for (int df = 0; df < 8; ++df)
#pragma unroll
    for (int qf = 0; qf < 2; ++qf) {
      f32x4 r = o[df][qf] * (qf ? li1 : li0);
      int q = qf * 16 + (lane & 15);
      int d = d0 + df * 16 + (lane >> 4) * 4;
      *(f32x4*)(outp + (size_t)q * D + d) = r;
    }
}

// ---------------- launcher ----------------
extern "C" void kernel_launch(void* const* d_in, const int* in_sizes, int n_in,
                              void* d_out, int out_size, void* d_ws, size_t ws_size,
                              hipStream_t stream) {
  const float* x  = (const float*)d_in[0];
  const float* Wq = (const float*)d_in[1];
  const float* bq = (const float*)d_in[2];
  const float* Wk = (const float*)d_in[3];
  const float* bk = (const float*)d_in[4];
  const float* Wv = (const float*)d_in[5];
  const float* bv = (const float*)d_in[6];
  float* out = (float*)d_out;

  char* ws = (char*)d_ws;
  // ws layout (bytes): xb 16MB | wb 6MB | qb 16MB | kb 16MB | vb 16MB | vt 16MB = 90.2MB
  ushort* xb = (ushort*)(ws);
  ushort* wb = (ushort*)(ws + 16777216);
  ushort* qb = (ushort*)(ws + 23068672);
  ushort* kb = (ushort*)(ws + 39845888);
  ushort* vb = (ushort*)(ws + 56623104);
  ushort* vt = (ushort*)(ws + 73400320);

  cvt_f32_to_bf16<<<8192, 256, 0, stream>>>(x,  xb, 2097152);
  cvt_f32_to_bf16<<<1024, 256, 0, stream>>>(Wq, wb,           262144);
  cvt_f32_to_bf16<<<1024, 256, 0, stream>>>(Wk, wb + 1048576, 262144);
  cvt_f32_to_bf16<<<1024, 256, 0, stream>>>(Wv, wb + 2097152, 262144);
  qkv_gemm<<<dim3(8, 64, 3), 256, 0, stream>>>(xb, wb, bq, bk, bv, qb, kb, vb);
  transpose_v<<<dim3(64, 32, 4), dim3(32, 8), 0, stream>>>(vb, vt);
  attn_fwd<<<dim3(64, 4), 512, 0, stream>>>(qb, kb, vt, out);
}

// Round 2
// 216.954 us; speedup vs baseline: 2.1873x; 2.1873x over previous
//
#include <hip/hip_runtime.h>
#include <hip/hip_bf16.h>

typedef __attribute__((ext_vector_type(4))) float f32x4;
typedef __attribute__((ext_vector_type(8))) short bf16x8;

#define MFMA16(a, b, c) __builtin_amdgcn_mfma_f32_16x16x32_bf16(a, b, c, 0, 0, 0)

constexpr int BATCH = 4;
constexpr int SEQ   = 2048;
constexpr int DIM   = 1024;

__device__ __forceinline__ ushort f2b(float f) {
  __hip_bfloat16 h = __float2bfloat16(f);
  union { __hip_bfloat16 h; ushort u; } cv; cv.h = h; return cv.u;
}
__device__ __forceinline__ float b2f(ushort u) {
  union { float f; unsigned int u; } cv; cv.u = ((unsigned int)u) << 16; return cv.f;
}

// ---------------- fp32 -> bf16 convert (vectorized) ----------------
__global__ __launch_bounds__(256) void cvt_f32_to_bf16(const float* __restrict__ in,
                                                       ushort* __restrict__ out, int n4) {
  int i = blockIdx.x * 256 + threadIdx.x;
  if (i < n4) {
    float4 v = reinterpret_cast<const float4*>(in)[i];
    ushort4 o;
    o.x = f2b(v.x); o.y = f2b(v.y); o.z = f2b(v.z); o.w = f2b(v.w);
    reinterpret_cast<ushort4*>(out)[i] = o;
  }
}

// ---------------- async global->LDS helper ----------------
__device__ __forceinline__ void gload_lds16(const void* g, void* l) {
  __builtin_amdgcn_global_load_lds(
      (const __attribute__((address_space(1))) unsigned int*)g,
      (__attribute__((address_space(3))) unsigned int*)l, 16, 0, 0);
}

// ---------------- QKV projection GEMM ----------------
// C[m][n] = sum_k X[m][k] * W[n][k] + bias[n], bf16 in, bf16 out, f32 acc.
__global__ __launch_bounds__(256) void qkv_gemm(
    const ushort* __restrict__ X,   // [8192][1024] bf16
    const ushort* __restrict__ W3,  // [3][1024][1024] bf16
    const float* __restrict__ bq, const float* __restrict__ bk, const float* __restrict__ bv,
    ushort* __restrict__ Qo, ushort* __restrict__ Ko, ushort* __restrict__ Vo)
{
  constexpr int K = DIM, N = DIM;
  __shared__ ushort As[2][128 * 32];
  __shared__ ushort Bs[2][128 * 32];
  const int which = blockIdx.z;
  const ushort* Wm = W3 + (size_t)which * N * K;
  const float* bias = which == 0 ? bq : (which == 1 ? bk : bv);
  ushort* C = which == 0 ? Qo : (which == 1 ? Ko : Vo);
  const int m0 = blockIdx.y * 128;
  const int n0 = blockIdx.x * 128;
  const int t = threadIdx.x;
  const int lane = t & 63;
  const int w = t >> 6;
  const int wm = w >> 1, wn = w & 1;

  f32x4 acc[4][4];
#pragma unroll
  for (int mi = 0; mi < 4; ++mi)
#pragma unroll
    for (int ni = 0; ni < 4; ++ni) acc[mi][ni] = 0.f;

  auto stage = [&](int buf, int kt) {
#pragma unroll
    for (int i = 0; i < 2; ++i) {
      int p = i * 256 + t;
      int row = p >> 2, ch = p & 3;
      const char* srcA = (const char*)X  + (size_t)(m0 + row) * (K * 2) + kt * 64 + ch * 16;
      const char* srcB = (const char*)Wm + (size_t)(n0 + row) * (K * 2) + kt * 64 + ch * 16;
      char* dstA = (char*)&As[buf][0] + (size_t)(i * 256 + (t & ~63)) * 16;
      char* dstB = (char*)&Bs[buf][0] + (size_t)(i * 256 + (t & ~63)) * 16;
      gload_lds16(srcA, dstA);
      gload_lds16(srcB, dstB);
    }
  };

  stage(0, 0);
  __syncthreads();
  int buf = 0;
  for (int kt = 0; kt < K / 32; ++kt) {
    if (kt + 1 < K / 32) stage(buf ^ 1, kt + 1);
    bf16x8 a[4], b[4];
#pragma unroll
    for (int i = 0; i < 4; ++i) {
      int rowA = wm * 64 + i * 16 + (lane & 15);
      a[i] = *(const bf16x8*)((const char*)&As[buf][0] + rowA * 64 + (lane >> 4) * 16);
      int rowB = wn * 64 + i * 16 + (lane & 15);
      b[i] = *(const bf16x8*)((const char*)&Bs[buf][0] + rowB * 64 + (lane >> 4) * 16);
    }
#pragma unroll
    for (int mi = 0; mi < 4; ++mi)
#pragma unroll
      for (int ni = 0; ni < 4; ++ni)
        acc[mi][ni] = MFMA16(a[mi], b[ni], acc[mi][ni]);
    __syncthreads();
    buf ^= 1;
  }

#pragma unroll
  for (int mi = 0; mi < 4; ++mi)
#pragma unroll
    for (int ni = 0; ni < 4; ++ni) {
      int gn = n0 + wn * 64 + ni * 16 + (lane & 15);
      float bb = bias[gn];
#pragma unroll
      for (int r = 0; r < 4; ++r) {
        int gm = m0 + wm * 64 + mi * 16 + (lane >> 4) * 4 + r;
        C[(size_t)gm * N + gn] = f2b(acc[mi][ni][r] + bb);
      }
    }
}

// ---------------- generic batched GEMM: C = scale * (A . B^T) ----------------
// A: [M][K] bf16 K-contig, B: [N][K] bf16 K-contig, C: [M][N] (bf16 or f32).
// grid: (N/128, M/128, BATCH). 128x128 tile, BK=32, 4 waves.
template <bool OUTF32>
__global__ __launch_bounds__(256) void gemm_bt(
    const ushort* __restrict__ Ag, const ushort* __restrict__ Bg, void* __restrict__ Cg,
    int N, int K, float scale, long sA, long sB, long sC)
{
  __shared__ ushort As[2][128 * 32];
  __shared__ ushort Bs[2][128 * 32];
  const int bz = blockIdx.z;
  const ushort* A = Ag + (size_t)bz * sA;
  const ushort* B = Bg + (size_t)bz * sB;
  const int m0 = blockIdx.y * 128;
  const int n0 = blockIdx.x * 128;
  const int t = threadIdx.x;
  const int lane = t & 63;
  const int w = t >> 6;
  const int wm = w >> 1, wn = w & 1;

  f32x4 acc[4][4];
#pragma unroll
  for (int mi = 0; mi < 4; ++mi)
#pragma unroll
    for (int ni = 0; ni < 4; ++ni) acc[mi][ni] = 0.f;

  auto stage = [&](int buf, int kt) {
#pragma unroll
    for (int i = 0; i < 2; ++i) {
      int p = i * 256 + t;
      int row = p >> 2, ch = p & 3;
      const char* srcA = (const char*)A + (size_t)(m0 + row) * (size_t)(K * 2) + kt * 64 + ch * 16;
      const char* srcB = (const char*)B + (size_t)(n0 + row) * (size_t)(K * 2) + kt * 64 + ch * 16;
      char* dstA = (char*)&As[buf][0] + (size_t)(i * 256 + (t & ~63)) * 16;
      char* dstB = (char*)&Bs[buf][0] + (size_t)(i * 256 + (t & ~63)) * 16;
      gload_lds16(srcA, dstA);
      gload_lds16(srcB, dstB);
    }
  };

  stage(0, 0);
  __syncthreads();
  int buf = 0;
  const int nkt = K / 32;
  for (int kt = 0; kt < nkt; ++kt) {
    if (kt + 1 < nkt) stage(buf ^ 1, kt + 1);
    bf16x8 a[4], b[4];
#pragma unroll
    for (int i = 0; i < 4; ++i) {
      int rowA = wm * 64 + i * 16 + (lane & 15);
      a[i] = *(const bf16x8*)((const char*)&As[buf][0] + rowA * 64 + (lane >> 4) * 16);
      int rowB = wn * 64 + i * 16 + (lane & 15);
      b[i] = *(const bf16x8*)((const char*)&Bs[buf][0] + rowB * 64 + (lane >> 4) * 16);
    }
#pragma unroll
    for (int mi = 0; mi < 4; ++mi)
#pragma unroll
      for (int ni = 0; ni < 4; ++ni)
        acc[mi][ni] = MFMA16(a[mi], b[ni], acc[mi][ni]);
    __syncthreads();
    buf ^= 1;
  }

#pragma unroll
  for (int mi = 0; mi < 4; ++mi)
#pragma unroll
    for (int ni = 0; ni < 4; ++ni) {
      int gn = n0 + wn * 64 + ni * 16 + (lane & 15);
#pragma unroll
      for (int r = 0; r < 4; ++r) {
        int gm = m0 + wm * 64 + mi * 16 + (lane >> 4) * 4 + r;
        float v = acc[mi][ni][r] * scale;
        if (OUTF32)
          ((float*)Cg)[(size_t)bz * sC + (size_t)gm * N + gn] = v;
        else
          ((ushort*)Cg)[(size_t)bz * sC + (size_t)gm * N + gn] = f2b(v);
      }
    }
}

// ---------------- row softmax, in place, bf16 ----------------
// one wave per row of 2048; block = 4 waves; grid = B*SEQ/4.
__global__ __launch_bounds__(256) void softmax_rows(ushort* __restrict__ SP) {
  const int lane = threadIdx.x & 63;
  const int w = threadIdx.x >> 6;
  const size_t row = (size_t)blockIdx.x * 4 + w;
  ushort* base = SP + row * SEQ;

  bf16x8 v[4];
  float s[32];
#pragma unroll
  for (int c = 0; c < 4; ++c) {
    v[c] = *(const bf16x8*)(base + c * 512 + lane * 8);
#pragma unroll
    for (int j = 0; j < 8; ++j) s[c * 8 + j] = b2f((ushort)v[c][j]);
  }
  float mx = s[0];
#pragma unroll
  for (int i = 1; i < 32; ++i) mx = fmaxf(mx, s[i]);
#pragma unroll
  for (int off = 1; off < 64; off <<= 1) mx = fmaxf(mx, __shfl_xor(mx, off));

  float sum = 0.f;
#pragma unroll
  for (int i = 0; i < 32; ++i) { s[i] = __expf(s[i] - mx); sum += s[i]; }
#pragma unroll
  for (int off = 1; off < 64; off <<= 1) sum += __shfl_xor(sum, off);
  float inv = 1.f / sum;

#pragma unroll
  for (int c = 0; c < 4; ++c) {
    bf16x8 o;
#pragma unroll
    for (int j = 0; j < 8; ++j) o[j] = (short)f2b(s[c * 8 + j] * inv);
    *(bf16x8*)(base + c * 512 + lane * 8) = o;
  }
}

// ---------------- V transpose: Vt[b][d][n] = V[b][n][d] ----------------
__global__ __launch_bounds__(256) void transpose_v(const ushort* __restrict__ Vb,
                                                   ushort* __restrict__ Vt) {
  __shared__ ushort tile[32][33];
  int b  = blockIdx.z;
  int n0 = blockIdx.x * 32, d0 = blockIdx.y * 32;
  int tx = threadIdx.x, ty = threadIdx.y;  // 32 x 8
#pragma unroll
  for (int j = 0; j < 32; j += 8)
    tile[ty + j][tx] = Vb[((size_t)b * SEQ + n0 + ty + j) * DIM + d0 + tx];
  __syncthreads();
#pragma unroll
  for (int j = 0; j < 32; j += 8)
    Vt[((size_t)b * DIM + d0 + ty + j) * SEQ + n0 + tx] = tile[tx][ty + j];
}

// ---------------- launcher ----------------
extern "C" void kernel_launch(void* const* d_in, const int* in_sizes, int n_in,
                              void* d_out, int out_size, void* d_ws, size_t ws_size,
                              hipStream_t stream) {
  const float* x  = (const float*)d_in[0];
  const float* Wq = (const float*)d_in[1];
  const float* bq = (const float*)d_in[2];
  const float* Wk = (const float*)d_in[3];
  const float* bk = (const float*)d_in[4];
  const float* Wv = (const float*)d_in[5];
  const float* bv = (const float*)d_in[6];
  float* out = (float*)d_out;

  char* ws = (char*)d_ws;
  // ws layout (bytes), total 90.2 MB:
  //   [0, 16M)      vb   (dead after transpose_v)   \__ S/P bf16 overlay [0, 33.5M)
  //   [16M, 32M)    xb   (dead after qkv_gemm)      /
  //   [32M, 38.3M)  wb
  //   [38.3M, ...)  qb | kb | vt  (16M each)
  ushort* vb = (ushort*)(ws);
  ushort* xb = (ushort*)(ws + 16777216);
  ushort* wb = (ushort*)(ws + 33554432);
  ushort* qb = (ushort*)(ws + 39845888);
  ushort* kb = (ushort*)(ws + 56623104);
  ushort* vt = (ushort*)(ws + 73400320);
  ushort* SP = (ushort*)(ws);  // [4][2048][2048] bf16, overlays vb+xb

  cvt_f32_to_bf16<<<8192, 256, 0, stream>>>(x,  xb, 2097152);
  cvt_f32_to_bf16<<<1024, 256, 0, stream>>>(Wq, wb,           262144);
  cvt_f32_to_bf16<<<1024, 256, 0, stream>>>(Wk, wb + 1048576, 262144);
  cvt_f32_to_bf16<<<1024, 256, 0, stream>>>(Wv, wb + 2097152, 262144);
  qkv_gemm<<<dim3(8, 64, 3), 256, 0, stream>>>(xb, wb, bq, bk, bv, qb, kb, vb);
  transpose_v<<<dim3(64, 32, 4), dim3(32, 8), 0, stream>>>(vb, vt);
  // S = Q K^T / sqrt(1024), bf16 into SP (overwrites vb/xb — both dead)
  gemm_bt<false><<<dim3(16, 16, 4), 256, 0, stream>>>(
      qb, kb, (void*)SP, SEQ, DIM, 0.03125f,
      (long)SEQ * DIM, (long)SEQ * DIM, (long)SEQ * SEQ);
  softmax_rows<<<2048, 256, 0, stream>>>(SP);
  // O = P V  via  A=P [2048][2048], B=Vt [1024][2048], f32 out
  gemm_bt<true><<<dim3(8, 16, 4), 256, 0, stream>>>(
      SP, vt, (void*)out, DIM, SEQ, 1.0f,
      (long)SEQ * SEQ, (long)DIM * SEQ, (long)SEQ * DIM);
}

// Round 3
// 203.065 us; speedup vs baseline: 2.3369x; 1.0684x over previous
//
#include <hip/hip_runtime.h>
#include <hip/hip_bf16.h>

typedef __attribute__((ext_vector_type(4))) float f32x4;
typedef __attribute__((ext_vector_type(8))) short bf16x8;

#define MFMA16(a, b, c) __builtin_amdgcn_mfma_f32_16x16x32_bf16(a, b, c, 0, 0, 0)

constexpr int BATCH = 4;
constexpr int SEQ   = 2048;
constexpr int DIM   = 1024;

__device__ __forceinline__ ushort f2b(float f) {
  __hip_bfloat16 h = __float2bfloat16(f);
  union { __hip_bfloat16 h; ushort u; } cv; cv.h = h; return cv.u;
}
__device__ __forceinline__ float b2f(ushort u) {
  union { float f; unsigned int u; } cv; cv.u = ((unsigned int)u) << 16; return cv.f;
}

// ---------------- fp32 -> bf16 convert (vectorized) ----------------
__global__ __launch_bounds__(256) void cvt_f32_to_bf16(const float* __restrict__ in,
                                                       ushort* __restrict__ out, int n4) {
  int i = blockIdx.x * 256 + threadIdx.x;
  if (i < n4) {
    float4 v = reinterpret_cast<const float4*>(in)[i];
    ushort4 o;
    o.x = f2b(v.x); o.y = f2b(v.y); o.z = f2b(v.z); o.w = f2b(v.w);
    reinterpret_cast<ushort4*>(out)[i] = o;
  }
}

// ---------------- async global->LDS helper ----------------
__device__ __forceinline__ void gload_lds16(const void* g, void* l) {
  __builtin_amdgcn_global_load_lds(
      (const __attribute__((address_space(1))) unsigned int*)g,
      (__attribute__((address_space(3))) unsigned int*)l, 16, 0, 0);
}

// ============ 256x256 8-phase GEMM (T2+T3+T4+T5, plain HIP) ============
// C = scale * (A . B^T) [+ bias].  A:[M][Kd] bf16 K-contig, B:[N'][Kd] bf16.
// 512 thr = 8 waves (2M x 4N), per-wave 128x64 out, BK=64, dbuf LDS 128 KiB.
// Swizzle: LDS linear dest; global SOURCE pre-swizzled; ds_read XOR-swizzled
// (byte ^= (row&7)<<4). vmcnt(4) once per K-tile (counted, never 0 mid-loop).
// QKV=true: N' = 3072 = 3 segments of 1024; route C/bias by n0>>10.
template <bool OUTF32, bool QKV>
__global__ __launch_bounds__(512) void gemm8(
    const ushort* __restrict__ Ag, const ushort* __restrict__ Bg,
    void* __restrict__ C0, void* __restrict__ C1, void* __restrict__ C2,
    const float* __restrict__ b0, const float* __restrict__ b1, const float* __restrict__ b2,
    int N, int Kd, float scale, long sA, long sB, long sC)
{
  __shared__ ushort As[2][256 * 64];
  __shared__ ushort Bs[2][256 * 64];

  // XCD-aware block swizzle (bijective: all our grids have nwg % 8 == 0)
  int nwg = gridDim.x * gridDim.y;
  int id = blockIdx.y * gridDim.x + blockIdx.x;
  int swz = (nwg & 7) ? id : ((id & 7) * (nwg >> 3) + (id >> 3));
  const int m0 = (swz / gridDim.x) * 256;
  const int n0 = (swz % gridDim.x) * 256;
  const int bz = blockIdx.z;
  const ushort* A = Ag + (size_t)bz * sA;
  const ushort* B = Bg + (size_t)bz * sB;
  const char* Ab = (const char*)A;
  const char* Bb = (const char*)B;
  const int t = threadIdx.x;
  const int lane = t & 63;
  const int w = t >> 6;
  const int wm = w >> 2;   // 0..1
  const int wn = w & 3;    // 0..3
  const size_t pA = (size_t)Kd * 2;
  const size_t pB = (size_t)Kd * 2;
  const int nt = Kd >> 6;  // K-tiles of 64 (>= 16 for all our shapes)

  // stage one 128-row half (16 KB): 2 x global_load_lds per thread,
  // linear LDS dest, inverse-swizzled global source.
  auto stageH = [&](ushort* ldsb, const char* gb, size_t pitch) {
#pragma unroll
    for (int j = 0; j < 2; ++j) {
      int g = j * 512 + t;
      int r = g >> 3;                                   // row within half
      int cb = ((g & 7) << 4) ^ ((r & 7) << 4);         // swizzled col byte
      gload_lds16(gb + (size_t)r * pitch + cb,
                  (char*)ldsb + (size_t)((j * 512 + (t & ~63)) << 4));
    }
  };
  // swizzled fragment read: logical (row, ks-slice) -> bf16x8
  auto ldfrag = [&](const ushort* base, int row, int ks) -> bf16x8 {
    int L = row * 128 + ks * 64 + ((lane >> 4) << 4);
    return *(const bf16x8*)((const char*)base + (L ^ ((row & 7) << 4)));
  };

  f32x4 acc[8][4];
#pragma unroll
  for (int i = 0; i < 8; ++i)
#pragma unroll
    for (int j = 0; j < 4; ++j) acc[i][j] = 0.f;

  bf16x8 a[4][2];      // current M-half frags
  bf16x8 bN[2][2][2];  // [nq][ni][ks]

#define DO_MFMA(mq, nq)                                                        \
  {                                                                            \
    __builtin_amdgcn_s_setprio(1);                                             \
    _Pragma("unroll") for (int mi = 0; mi < 4; ++mi)                           \
        _Pragma("unroll") for (int ni = 0; ni < 2; ++ni) {                     \
      acc[(mq)*4 + mi][(nq)*2 + ni] =                                          \
          MFMA16(a[mi][0], bN[nq][ni][0], acc[(mq)*4 + mi][(nq)*2 + ni]);      \
      acc[(mq)*4 + mi][(nq)*2 + ni] =                                          \
          MFMA16(a[mi][1], bN[nq][ni][1], acc[(mq)*4 + mi][(nq)*2 + ni]);      \
    }                                                                          \
    __builtin_amdgcn_s_setprio(0);                                             \
  }
#define BAR() __builtin_amdgcn_s_barrier()

  // ---- prologue: B0(0),B1(0),A0(0),A1(0),B0(1),B1(1); vmcnt(4) -> tile0 in ----
  stageH(&Bs[0][0],        Bb + (size_t)n0 * pB,                pB);
  stageH(&Bs[0][128 * 64], Bb + (size_t)(n0 + 128) * pB,        pB);
  stageH(&As[0][0],        Ab + (size_t)m0 * pA,                pA);
  stageH(&As[0][128 * 64], Ab + (size_t)(m0 + 128) * pA,        pA);
  stageH(&Bs[1][0],        Bb + (size_t)n0 * pB + 128,          pB);
  stageH(&Bs[1][128 * 64], Bb + (size_t)(n0 + 128) * pB + 128,  pB);
  asm volatile("s_waitcnt vmcnt(4)" ::: "memory");
  BAR();

  for (int tt = 0; tt < nt; ++tt) {
    const int buf = tt & 1;
    const ushort* Ac = &As[buf][0];
    const ushort* Bc = &Bs[buf][0];
    const size_t ko1 = (size_t)(tt + 1) * 128;  // byte offset of tile t+1
    const size_t ko2 = (size_t)(tt + 2) * 128;

    // ---- P0: read A[M0] + B[N0]; stage A-half0(t+1) ----
#pragma unroll
    for (int mi = 0; mi < 4; ++mi) {
      int r = wm * 128 + mi * 16 + (lane & 15);
      a[mi][0] = ldfrag(Ac, r, 0);
      a[mi][1] = ldfrag(Ac, r, 1);
    }
#pragma unroll
    for (int ni = 0; ni < 2; ++ni) {
      int r = wn * 64 + ni * 16 + (lane & 15);
      bN[0][ni][0] = ldfrag(Bc, r, 0);
      bN[0][ni][1] = ldfrag(Bc, r, 1);
    }
    if (tt + 1 < nt) stageH(&As[buf ^ 1][0], Ab + (size_t)m0 * pA + ko1, pA);
    BAR();
    DO_MFMA(0, 0);
    BAR();

    // ---- P1: read B[N1]; stage A-half1(t+1) ----
#pragma unroll
    for (int ni = 0; ni < 2; ++ni) {
      int r = wn * 64 + (2 + ni) * 16 + (lane & 15);
      bN[1][ni][0] = ldfrag(Bc, r, 0);
      bN[1][ni][1] = ldfrag(Bc, r, 1);
    }
    if (tt + 1 < nt)
      stageH(&As[buf ^ 1][128 * 64], Ab + (size_t)(m0 + 128) * pA + ko1, pA);
    BAR();
    DO_MFMA(0, 1);
    BAR();

    // ---- P2: read A[M1]; stage B-half0(t+2) ----
#pragma unroll
    for (int mi = 0; mi < 4; ++mi) {
      int r = wm * 128 + (4 + mi) * 16 + (lane & 15);
      a[mi][0] = ldfrag(Ac, r, 0);
      a[mi][1] = ldfrag(Ac, r, 1);
    }
    if (tt + 2 < nt) stageH(&Bs[buf][0], Bb + (size_t)n0 * pB + ko2, pB);
    BAR();
    DO_MFMA(1, 1);
    BAR();

    // ---- P3: stage B-half1(t+2); counted vmcnt -> tile t+1 landed ----
    if (tt + 2 < nt)
      stageH(&Bs[buf][128 * 64], Bb + (size_t)(n0 + 128) * pB + ko2, pB);
    if (tt + 2 < nt) {
      asm volatile("s_waitcnt vmcnt(4)" ::: "memory");
    } else if (tt + 1 < nt) {
      asm volatile("s_waitcnt vmcnt(0)" ::: "memory");
    }
    BAR();
    DO_MFMA(1, 0);
    BAR();
  }
#undef DO_MFMA
#undef BAR

  // ---- epilogue ----
  const int seg = QKV ? (n0 >> 10) : 0;
  const int n0l = QKV ? (n0 & 1023) : n0;
  const float* biasp = QKV ? (seg == 0 ? b0 : (seg == 1 ? b1 : b2)) : nullptr;
  void* Cp = QKV ? (seg == 0 ? C0 : (seg == 1 ? C1 : C2)) : C0;
  float* Cf = (float*)Cp + (size_t)bz * sC;
  ushort* Ch = (ushort*)Cp + (size_t)bz * sC;

#pragma unroll
  for (int mf = 0; mf < 8; ++mf)
#pragma unroll
    for (int nf = 0; nf < 4; ++nf) {
      int gn = n0l + wn * 64 + nf * 16 + (lane & 15);
      float bb = QKV ? biasp[gn] : 0.f;
#pragma unroll
      for (int r = 0; r < 4; ++r) {
        int gm = m0 + wm * 128 + mf * 16 + (lane >> 4) * 4 + r;
        float v = acc[mf][nf][r] * scale + bb;
        if (OUTF32) Cf[(size_t)gm * N + gn] = v;
        else        Ch[(size_t)gm * N + gn] = f2b(v);
      }
    }
}

// ---------------- row softmax, in place, bf16 ----------------
__global__ __launch_bounds__(256) void softmax_rows(ushort* __restrict__ SP) {
  const int lane = threadIdx.x & 63;
  const int w = threadIdx.x >> 6;
  const size_t row = (size_t)blockIdx.x * 4 + w;
  ushort* base = SP + row * SEQ;

  bf16x8 v[4];
  float s[32];
#pragma unroll
  for (int c = 0; c < 4; ++c) {
    v[c] = *(const bf16x8*)(base + c * 512 + lane * 8);
#pragma unroll
    for (int j = 0; j < 8; ++j) s[c * 8 + j] = b2f((ushort)v[c][j]);
  }
  float mx = s[0];
#pragma unroll
  for (int i = 1; i < 32; ++i) mx = fmaxf(mx, s[i]);
#pragma unroll
  for (int off = 1; off < 64; off <<= 1) mx = fmaxf(mx, __shfl_xor(mx, off));

  float sum = 0.f;
#pragma unroll
  for (int i = 0; i < 32; ++i) { s[i] = __expf(s[i] - mx); sum += s[i]; }
#pragma unroll
  for (int off = 1; off < 64; off <<= 1) sum += __shfl_xor(sum, off);
  float inv = 1.f / sum;

#pragma unroll
  for (int c = 0; c < 4; ++c) {
    bf16x8 o;
#pragma unroll
    for (int j = 0; j < 8; ++j) o[j] = (short)f2b(s[c * 8 + j] * inv);
    *(bf16x8*)(base + c * 512 + lane * 8) = o;
  }
}

// ---------------- V transpose: Vt[b][d][n] = V[b][n][d] ----------------
__global__ __launch_bounds__(256) void transpose_v(const ushort* __restrict__ Vb,
                                                   ushort* __restrict__ Vt) {
  __shared__ ushort tile[32][33];
  int b  = blockIdx.z;
  int n0 = blockIdx.x * 32, d0 = blockIdx.y * 32;
  int tx = threadIdx.x, ty = threadIdx.y;  // 32 x 8
#pragma unroll
  for (int j = 0; j < 32; j += 8)
    tile[ty + j][tx] = Vb[((size_t)b * SEQ + n0 + ty + j) * DIM + d0 + tx];
  __syncthreads();
#pragma unroll
  for (int j = 0; j < 32; j += 8)
    Vt[((size_t)b * DIM + d0 + ty + j) * SEQ + n0 + tx] = tile[tx][ty + j];
}

// ---------------- launcher ----------------
extern "C" void kernel_launch(void* const* d_in, const int* in_sizes, int n_in,
                              void* d_out, int out_size, void* d_ws, size_t ws_size,
                              hipStream_t stream) {
  const float* x  = (const float*)d_in[0];
  const float* Wq = (const float*)d_in[1];
  const float* bq = (const float*)d_in[2];
  const float* Wk = (const float*)d_in[3];
  const float* bk = (const float*)d_in[4];
  const float* Wv = (const float*)d_in[5];
  const float* bv = (const float*)d_in[6];
  float* out = (float*)d_out;

  char* ws = (char*)d_ws;
  // ws layout (bytes), total 90.2 MB:
  //   [0, 16M)      vb   (dead after transpose_v)   \__ SP bf16 overlay [0, 32MiB)
  //   [16M, 32M)    xb   (dead after qkv gemm)      /
  //   [32M, 38.3M)  wb   (= Wq|Wk|Wv bf16, 3072 rows x 1024)
  //   [38.3M, ...)  qb | kb | vt  (16M each)
  ushort* vb = (ushort*)(ws);
  ushort* xb = (ushort*)(ws + 16777216);
  ushort* wb = (ushort*)(ws + 33554432);
  ushort* qb = (ushort*)(ws + 39845888);
  ushort* kb = (ushort*)(ws + 56623104);
  ushort* vt = (ushort*)(ws + 73400320);
  ushort* SP = (ushort*)(ws);  // [4][2048][2048] bf16, overlays vb+xb

  cvt_f32_to_bf16<<<8192, 256, 0, stream>>>(x,  xb, 2097152);
  cvt_f32_to_bf16<<<1024, 256, 0, stream>>>(Wq, wb,           262144);
  cvt_f32_to_bf16<<<1024, 256, 0, stream>>>(Wk, wb + 1048576, 262144);
  cvt_f32_to_bf16<<<1024, 256, 0, stream>>>(Wv, wb + 2097152, 262144);

  // QKV: [8192 x 3072] = X[8192x1024] . W3^T, bias, bf16 out routed to qb/kb/vb
  gemm8<false, true><<<dim3(12, 32, 1), 512, 0, stream>>>(
      xb, wb, qb, kb, vb, bq, bk, bv, DIM, DIM, 1.0f, 0, 0, 0);
  transpose_v<<<dim3(64, 32, 4), dim3(32, 8), 0, stream>>>(vb, vt);
  // S = Q K^T / 32, bf16 into SP
  gemm8<false, false><<<dim3(8, 8, 4), 512, 0, stream>>>(
      qb, kb, SP, nullptr, nullptr, nullptr, nullptr, nullptr,
      SEQ, DIM, 0.03125f, (long)SEQ * DIM, (long)SEQ * DIM, (long)SEQ * SEQ);
  softmax_rows<<<2048, 256, 0, stream>>>(SP);
  // O = P V : A=P [2048][2048], B=Vt [1024][2048], f32 out
  gemm8<true, false><<<dim3(4, 8, 4), 512, 0, stream>>>(
      SP, vt, out, nullptr, nullptr, nullptr, nullptr, nullptr,
      DIM, SEQ, 1.0f, (long)SEQ * SEQ, (long)DIM * SEQ, (long)SEQ * DIM);
}

// Round 4
// 195.840 us; speedup vs baseline: 2.4231x; 1.0369x over previous
//
#include <hip/hip_runtime.h>
#include <hip/hip_bf16.h>

typedef __attribute__((ext_vector_type(4))) float f32x4;
typedef __attribute__((ext_vector_type(8))) short bf16x8;

#define MFMA16(a, b, c) __builtin_amdgcn_mfma_f32_16x16x32_bf16(a, b, c, 0, 0, 0)

constexpr int BATCH = 4;
constexpr int SEQ   = 2048;
constexpr int DIM   = 1024;

__device__ __forceinline__ ushort f2b(float f) {
  __hip_bfloat16 h = __float2bfloat16(f);
  union { __hip_bfloat16 h; ushort u; } cv; cv.h = h; return cv.u;
}
__device__ __forceinline__ float b2f(ushort u) {
  union { float f; unsigned int u; } cv; cv.u = ((unsigned int)u) << 16; return cv.f;
}

// ---------------- fp32 -> bf16 convert (vectorized) ----------------
__global__ __launch_bounds__(256) void cvt_f32_to_bf16(const float* __restrict__ in,
                                                       ushort* __restrict__ out, int n4) {
  int i = blockIdx.x * 256 + threadIdx.x;
  if (i < n4) {
    float4 v = reinterpret_cast<const float4*>(in)[i];
    ushort4 o;
    o.x = f2b(v.x); o.y = f2b(v.y); o.z = f2b(v.z); o.w = f2b(v.w);
    reinterpret_cast<ushort4*>(out)[i] = o;
  }
}

// ---------------- async global->LDS helper ----------------
__device__ __forceinline__ void gload_lds16(const void* g, void* l) {
  __builtin_amdgcn_global_load_lds(
      (const __attribute__((address_space(1))) unsigned int*)g,
      (__attribute__((address_space(3))) unsigned int*)l, 16, 0, 0);
}

// ============ 256xBN 8-wave pipelined GEMM (T2+T3+T4+T5) ============
// C = scale * (A . B^T) [+ bias].  A:[M][Kd] bf16 K-contig, B:[N'][Kd] bf16.
// BN=256: 8 waves 2Mx4N (wave 128x64), 4 phases/K-tile, 16 MFMA each,
//         vmcnt(4)/K-tile, LDS 128 KiB.  [proven m201 schedule]
// BN=128: 8 waves 4Mx2N (wave 64x64), 2 phases/K-tile, 16 MFMA each,
//         vmcnt(2)/K-tile, LDS 96 KiB.  [same per-phase shape, half N]
// Swizzle: LDS linear dest; global SOURCE pre-swizzled; ds_read XOR-swizzled.
// QKV=true: N' = 3072 = 3 segments of 1024; route C/bias by n0>>10.
template <int BN_, bool OUTF32, bool QKV>
__global__ __launch_bounds__(512) void gemm8(
    const ushort* __restrict__ Ag, const ushort* __restrict__ Bg,
    void* __restrict__ C0, void* __restrict__ C1, void* __restrict__ C2,
    const float* __restrict__ b0, const float* __restrict__ b1, const float* __restrict__ b2,
    int N, int Kd, float scale, long sA, long sB, long sC)
{
  constexpr int BM = 256;
  constexpr int BH = BN_ / 128;             // B 128-row halves per K-tile (2 or 1)
  constexpr int WN = (BN_ == 256) ? 4 : 2;
  constexpr int WM = 8 / WN;
  constexpr int PWM = BM / WM;              // per-wave rows: 128 or 64
  constexpr int RM = PWM / 16;              // 8 or 4
  constexpr int VCNT = 2 * BH;              // steady-state counted vmcnt

  __shared__ ushort As[2][BM * 64];
  __shared__ ushort Bs[2][BN_ * 64];

  // XCD-aware swizzle (bijective; all grids here have nwg % 8 == 0)
  int nwg = gridDim.x * gridDim.y;
  int id = blockIdx.y * gridDim.x + blockIdx.x;
  int swz = (nwg & 7) ? id : ((id & 7) * (nwg >> 3) + (id >> 3));
  const int m0 = (swz / gridDim.x) * BM;
  const int n0 = (swz % gridDim.x) * BN_;
  const int bz = blockIdx.z;
  const char* Ab = (const char*)(Ag + (size_t)bz * sA);
  const char* Bb = (const char*)(Bg + (size_t)bz * sB);
  const int t = threadIdx.x;
  const int lane = t & 63;
  const int w = t >> 6;
  const int wm = w / WN;
  const int wn = w % WN;
  const size_t pA = (size_t)Kd * 2;
  const size_t pB = (size_t)Kd * 2;
  const int nt = Kd >> 6;

  // stage one 128-row half (16 KB): linear LDS dest, inverse-swizzled source.
  auto stageH = [&](ushort* ldsb, const char* gb, size_t pitch) {
#pragma unroll
    for (int j = 0; j < 2; ++j) {
      int g = j * 512 + t;
      int r = g >> 3;
      int cb = ((g & 7) << 4) ^ ((r & 7) << 4);
      gload_lds16(gb + (size_t)r * pitch + cb,
                  (char*)ldsb + (size_t)((j * 512 + (t & ~63)) << 4));
    }
  };
  auto ldfrag = [&](const ushort* base, int row, int ks) -> bf16x8 {
    int L = row * 128 + ks * 64 + ((lane >> 4) << 4);
    return *(const bf16x8*)((const char*)base + (L ^ ((row & 7) << 4)));
  };

  f32x4 acc[RM][4];
#pragma unroll
  for (int i = 0; i < RM; ++i)
#pragma unroll
    for (int j = 0; j < 4; ++j) acc[i][j] = 0.f;

  bf16x8 a[4][2];   // current M-quadrant frags (128-path uses [0..1])
  bf16x8 bN[4][2];  // B frags: 256-path [nq*2+ni], 128-path [nf]

#define BAR() __builtin_amdgcn_s_barrier()

  // ---- prologue: B(0) halves, A(0) halves, B(1) halves; vmcnt(VCNT) ----
  stageH(&Bs[0][0], Bb + (size_t)n0 * pB, pB);
  if (BH == 2) stageH(&Bs[0][128 * 64], Bb + (size_t)(n0 + 128) * pB, pB);
  stageH(&As[0][0], Ab + (size_t)m0 * pA, pA);
  stageH(&As[0][128 * 64], Ab + (size_t)(m0 + 128) * pA, pA);
  stageH(&Bs[1][0], Bb + (size_t)n0 * pB + 128, pB);
  if (BH == 2) stageH(&Bs[1][128 * 64], Bb + (size_t)(n0 + 128) * pB + 128, pB);
  if (BH == 2) asm volatile("s_waitcnt vmcnt(4)" ::: "memory");
  else         asm volatile("s_waitcnt vmcnt(2)" ::: "memory");
  BAR();

  for (int tt = 0; tt < nt; ++tt) {
    const int buf = tt & 1;
    const ushort* Ac = &As[buf][0];
    const ushort* Bc = &Bs[buf][0];
    const size_t ko1 = (size_t)(tt + 1) * 128;
    const size_t ko2 = (size_t)(tt + 2) * 128;

    if constexpr (BN_ == 256) {
      // ---- P0: read A[M0] + B[N0]; stage A-half0(t+1) ----
#pragma unroll
      for (int mi = 0; mi < 4; ++mi) {
        int r = wm * 128 + mi * 16 + (lane & 15);
        a[mi][0] = ldfrag(Ac, r, 0); a[mi][1] = ldfrag(Ac, r, 1);
      }
#pragma unroll
      for (int ni = 0; ni < 2; ++ni) {
        int r = wn * 64 + ni * 16 + (lane & 15);
        bN[ni][0] = ldfrag(Bc, r, 0); bN[ni][1] = ldfrag(Bc, r, 1);
      }
      if (tt + 1 < nt) stageH(&As[buf ^ 1][0], Ab + (size_t)m0 * pA + ko1, pA);
      BAR();
      __builtin_amdgcn_s_setprio(1);
#pragma unroll
      for (int mi = 0; mi < 4; ++mi)
#pragma unroll
        for (int ni = 0; ni < 2; ++ni) {
          acc[mi][ni] = MFMA16(a[mi][0], bN[ni][0], acc[mi][ni]);
          acc[mi][ni] = MFMA16(a[mi][1], bN[ni][1], acc[mi][ni]);
        }
      __builtin_amdgcn_s_setprio(0);
      BAR();
      // ---- P1: read B[N1]; stage A-half1(t+1) ----
#pragma unroll
      for (int ni = 0; ni < 2; ++ni) {
        int r = wn * 64 + (2 + ni) * 16 + (lane & 15);
        bN[2 + ni][0] = ldfrag(Bc, r, 0); bN[2 + ni][1] = ldfrag(Bc, r, 1);
      }
      if (tt + 1 < nt)
        stageH(&As[buf ^ 1][128 * 64], Ab + (size_t)(m0 + 128) * pA + ko1, pA);
      BAR();
      __builtin_amdgcn_s_setprio(1);
#pragma unroll
      for (int mi = 0; mi < 4; ++mi)
#pragma unroll
        for (int ni = 0; ni < 2; ++ni) {
          acc[mi][2 + ni] = MFMA16(a[mi][0], bN[2 + ni][0], acc[mi][2 + ni]);
          acc[mi][2 + ni] = MFMA16(a[mi][1], bN[2 + ni][1], acc[mi][2 + ni]);
        }
      __builtin_amdgcn_s_setprio(0);
      BAR();
      // ---- P2: read A[M1]; stage B-half0(t+2) ----
#pragma unroll
      for (int mi = 0; mi < 4; ++mi) {
        int r = wm * 128 + (4 + mi) * 16 + (lane & 15);
        a[mi][0] = ldfrag(Ac, r, 0); a[mi][1] = ldfrag(Ac, r, 1);
      }
      if (tt + 2 < nt) stageH(&Bs[buf][0], Bb + (size_t)n0 * pB + ko2, pB);
      BAR();
      __builtin_amdgcn_s_setprio(1);
#pragma unroll
      for (int mi = 0; mi < 4; ++mi)
#pragma unroll
        for (int ni = 0; ni < 2; ++ni) {
          acc[4 + mi][2 + ni] = MFMA16(a[mi][0], bN[2 + ni][0], acc[4 + mi][2 + ni]);
          acc[4 + mi][2 + ni] = MFMA16(a[mi][1], bN[2 + ni][1], acc[4 + mi][2 + ni]);
        }
      __builtin_amdgcn_s_setprio(0);
      BAR();
      // ---- P3: stage B-half1(t+2); counted vmcnt ----
      if (tt + 2 < nt)
        stageH(&Bs[buf][128 * 64], Bb + (size_t)(n0 + 128) * pB + ko2, pB);
      if (tt + 2 < nt)      asm volatile("s_waitcnt vmcnt(4)" ::: "memory");
      else if (tt + 1 < nt) asm volatile("s_waitcnt vmcnt(0)" ::: "memory");
      BAR();
      __builtin_amdgcn_s_setprio(1);
#pragma unroll
      for (int mi = 0; mi < 4; ++mi)
#pragma unroll
        for (int ni = 0; ni < 2; ++ni) {
          acc[4 + mi][ni] = MFMA16(a[mi][0], bN[ni][0], acc[4 + mi][ni]);
          acc[4 + mi][ni] = MFMA16(a[mi][1], bN[ni][1], acc[4 + mi][ni]);
        }
      __builtin_amdgcn_s_setprio(0);
      BAR();
    } else {
      // ======== BN=128: 2 phases/K-tile, 16 MFMA each ========
      // ---- P0: read A[M0] (4) + B[all] (8); stage A-half0(t+1) ----
#pragma unroll
      for (int mi = 0; mi < 2; ++mi) {
        int r = wm * 64 + mi * 16 + (lane & 15);
        a[mi][0] = ldfrag(Ac, r, 0); a[mi][1] = ldfrag(Ac, r, 1);
      }
#pragma unroll
      for (int nf = 0; nf < 4; ++nf) {
        int r = wn * 64 + nf * 16 + (lane & 15);
        bN[nf][0] = ldfrag(Bc, r, 0); bN[nf][1] = ldfrag(Bc, r, 1);
      }
      if (tt + 1 < nt) stageH(&As[buf ^ 1][0], Ab + (size_t)m0 * pA + ko1, pA);
      BAR();
      __builtin_amdgcn_s_setprio(1);
#pragma unroll
      for (int mi = 0; mi < 2; ++mi)
#pragma unroll
        for (int nf = 0; nf < 4; ++nf) {
          acc[mi][nf] = MFMA16(a[mi][0], bN[nf][0], acc[mi][nf]);
          acc[mi][nf] = MFMA16(a[mi][1], bN[nf][1], acc[mi][nf]);
        }
      __builtin_amdgcn_s_setprio(0);
      BAR();
      // ---- P1: read A[M1]; stage A-half1(t+1) + B(t+2); vmcnt(2) ----
#pragma unroll
      for (int mi = 0; mi < 2; ++mi) {
        int r = wm * 64 + (2 + mi) * 16 + (lane & 15);
        a[mi][0] = ldfrag(Ac, r, 0); a[mi][1] = ldfrag(Ac, r, 1);
      }
      if (tt + 1 < nt)
        stageH(&As[buf ^ 1][128 * 64], Ab + (size_t)(m0 + 128) * pA + ko1, pA);
      if (tt + 2 < nt) stageH(&Bs[buf][0], Bb + (size_t)n0 * pB + ko2, pB);
      if (tt + 2 < nt)      asm volatile("s_waitcnt vmcnt(2)" ::: "memory");
      else if (tt + 1 < nt) asm volatile("s_waitcnt vmcnt(0)" ::: "memory");
      BAR();
      __builtin_amdgcn_s_setprio(1);
#pragma unroll
      for (int mi = 0; mi < 2; ++mi)
#pragma unroll
        for (int nf = 0; nf < 4; ++nf) {
          acc[2 + mi][nf] = MFMA16(a[mi][0], bN[nf][0], acc[2 + mi][nf]);
          acc[2 + mi][nf] = MFMA16(a[mi][1], bN[nf][1], acc[2 + mi][nf]);
        }
      __builtin_amdgcn_s_setprio(0);
      BAR();
    }
  }
#undef BAR

  // ---- epilogue ----
  const int seg = QKV ? (n0 >> 10) : 0;
  const int n0l = QKV ? (n0 & 1023) : n0;
  const float* biasp = QKV ? (seg == 0 ? b0 : (seg == 1 ? b1 : b2)) : nullptr;
  void* Cp = QKV ? (seg == 0 ? C0 : (seg == 1 ? C1 : C2)) : C0;
  float* Cf = (float*)Cp + (size_t)bz * sC;
  ushort* Ch = (ushort*)Cp + (size_t)bz * sC;

#pragma unroll
  for (int mf = 0; mf < RM; ++mf)
#pragma unroll
    for (int nf = 0; nf < 4; ++nf) {
      int gn = n0l + wn * 64 + nf * 16 + (lane & 15);
      float bb = QKV ? biasp[gn] : 0.f;
#pragma unroll
      for (int r = 0; r < 4; ++r) {
        int gm = m0 + wm * PWM + mf * 16 + (lane >> 4) * 4 + r;
        float v = acc[mf][nf][r] * scale + bb;
        if (OUTF32) Cf[(size_t)gm * N + gn] = v;
        else        Ch[(size_t)gm * N + gn] = f2b(v);
      }
    }
}

// ---------------- row softmax, in place, bf16 ----------------
__global__ __launch_bounds__(256) void softmax_rows(ushort* __restrict__ SP) {
  const int lane = threadIdx.x & 63;
  const int w = threadIdx.x >> 6;
  const size_t row = (size_t)blockIdx.x * 4 + w;
  ushort* base = SP + row * SEQ;

  bf16x8 v[4];
  float s[32];
#pragma unroll
  for (int c = 0; c < 4; ++c) {
    v[c] = *(const bf16x8*)(base + c * 512 + lane * 8);
#pragma unroll
    for (int j = 0; j < 8; ++j) s[c * 8 + j] = b2f((ushort)v[c][j]);
  }
  float mx = s[0];
#pragma unroll
  for (int i = 1; i < 32; ++i) mx = fmaxf(mx, s[i]);
#pragma unroll
  for (int off = 1; off < 64; off <<= 1) mx = fmaxf(mx, __shfl_xor(mx, off));

  float sum = 0.f;
#pragma unroll
  for (int i = 0; i < 32; ++i) { s[i] = __expf(s[i] - mx); sum += s[i]; }
#pragma unroll
  for (int off = 1; off < 64; off <<= 1) sum += __shfl_xor(sum, off);
  float inv = 1.f / sum;

#pragma unroll
  for (int c = 0; c < 4; ++c) {
    bf16x8 o;
#pragma unroll
    for (int j = 0; j < 8; ++j) o[j] = (short)f2b(s[c * 8 + j] * inv);
    *(bf16x8*)(base + c * 512 + lane * 8) = o;
  }
}

// ---------------- V transpose: Vt[b][d][n] = V[b][n][d] ----------------
__global__ __launch_bounds__(256) void transpose_v(const ushort* __restrict__ Vb,
                                                   ushort* __restrict__ Vt) {
  __shared__ ushort tile[32][33];
  int b  = blockIdx.z;
  int n0 = blockIdx.x * 32, d0 = blockIdx.y * 32;
  int tx = threadIdx.x, ty = threadIdx.y;  // 32 x 8
#pragma unroll
  for (int j = 0; j < 32; j += 8)
    tile[ty + j][tx] = Vb[((size_t)b * SEQ + n0 + ty + j) * DIM + d0 + tx];
  __syncthreads();
#pragma unroll
  for (int j = 0; j < 32; j += 8)
    Vt[((size_t)b * DIM + d0 + ty + j) * SEQ + n0 + tx] = tile[tx][ty + j];
}

// ---------------- launcher ----------------
extern "C" void kernel_launch(void* const* d_in, const int* in_sizes, int n_in,
                              void* d_out, int out_size, void* d_ws, size_t ws_size,
                              hipStream_t stream) {
  const float* x  = (const float*)d_in[0];
  const float* Wq = (const float*)d_in[1];
  const float* bq = (const float*)d_in[2];
  const float* Wk = (const float*)d_in[3];
  const float* bk = (const float*)d_in[4];
  const float* Wv = (const float*)d_in[5];
  const float* bv = (const float*)d_in[6];
  float* out = (float*)d_out;

  char* ws = (char*)d_ws;
  // ws layout (bytes), total 90.2 MB:
  //   [0, 16M)      vb   (dead after transpose_v)   \__ SP bf16 overlay [0, 32MiB)
  //   [16M, 32M)    xb   (dead after qkv gemm)      /
  //   [32M, 38.3M)  wb   (= Wq|Wk|Wv bf16, 3072 rows x 1024)
  //   [38.3M, ...)  qb | kb | vt  (16M each)
  ushort* vb = (ushort*)(ws);
  ushort* xb = (ushort*)(ws + 16777216);
  ushort* wb = (ushort*)(ws + 33554432);
  ushort* qb = (ushort*)(ws + 39845888);
  ushort* kb = (ushort*)(ws + 56623104);
  ushort* vt = (ushort*)(ws + 73400320);
  ushort* SP = (ushort*)(ws);  // [4][2048][2048] bf16, overlays vb+xb

  cvt_f32_to_bf16<<<8192, 256, 0, stream>>>(x,  xb, 2097152);
  cvt_f32_to_bf16<<<1024, 256, 0, stream>>>(Wq, wb,           262144);
  cvt_f32_to_bf16<<<1024, 256, 0, stream>>>(Wk, wb + 1048576, 262144);
  cvt_f32_to_bf16<<<1024, 256, 0, stream>>>(Wv, wb + 2097152, 262144);

  // QKV: [8192 x 3072] = X . W3^T + bias -> qb/kb/vb.  768 blocks = 3 rounds.
  gemm8<128, false, true><<<dim3(24, 32, 1), 512, 0, stream>>>(
      xb, wb, qb, kb, vb, bq, bk, bv, DIM, DIM, 1.0f, 0, 0, 0);
  transpose_v<<<dim3(64, 32, 4), dim3(32, 8), 0, stream>>>(vb, vt);
  // S = Q K^T / 32 -> SP.  256 blocks (proven 256-sq schedule).
  gemm8<256, false, false><<<dim3(8, 8, 4), 512, 0, stream>>>(
      qb, kb, SP, nullptr, nullptr, nullptr, nullptr, nullptr,
      SEQ, DIM, 0.03125f, (long)SEQ * DIM, (long)SEQ * DIM, (long)SEQ * SEQ);
  softmax_rows<<<2048, 256, 0, stream>>>(SP);
  // O = P V : A=P [2048][2048], B=Vt [1024][2048], f32 out.  256 blocks.
  gemm8<128, true, false><<<dim3(8, 8, 4), 512, 0, stream>>>(
      SP, vt, out, nullptr, nullptr, nullptr, nullptr, nullptr,
      DIM, SEQ, 1.0f, (long)SEQ * SEQ, (long)DIM * SEQ, (long)SEQ * DIM);
}

// Round 5
// 179.783 us; speedup vs baseline: 2.6395x; 1.0893x over previous
//
#include <hip/hip_runtime.h>
#include <hip/hip_bf16.h>

typedef __attribute__((ext_vector_type(4))) float f32x4;
typedef __attribute__((ext_vector_type(8))) short bf16x8;

#define MFMA16(a, b, c) __builtin_amdgcn_mfma_f32_16x16x32_bf16(a, b, c, 0, 0, 0)

constexpr int BATCH = 4;
constexpr int SEQ   = 2048;
constexpr int DIM   = 1024;

__device__ __forceinline__ ushort f2b(float f) {
  __hip_bfloat16 h = __float2bfloat16(f);
  union { __hip_bfloat16 h; ushort u; } cv; cv.h = h; return cv.u;
}
__device__ __forceinline__ float b2f(ushort u) {
  union { float f; unsigned int u; } cv; cv.u = ((unsigned int)u) << 16; return cv.f;
}

// ---------------- fused fp32 -> bf16 convert: x + Wq + Wk + Wv ----------------
__global__ __launch_bounds__(256) void cvt_all(
    const float* __restrict__ x, const float* __restrict__ wq,
    const float* __restrict__ wk, const float* __restrict__ wv,
    ushort* __restrict__ xb, ushort* __restrict__ wb) {
  int i = blockIdx.x * 256 + threadIdx.x;     // float4 index, 2883584 total
  const float* src; ushort* dst; int off;
  if (i < 2097152) { src = x; dst = xb; off = i; }
  else {
    int j = i - 2097152;
    int s = j >> 18;                          // 262144 float4 per W
    off = j & 262143;
    src = (s == 0) ? wq : (s == 1) ? wk : wv;
    dst = wb + s * 1048576;
  }
  float4 v = reinterpret_cast<const float4*>(src)[off];
  ushort4 o;
  o.x = f2b(v.x); o.y = f2b(v.y); o.z = f2b(v.z); o.w = f2b(v.w);
  reinterpret_cast<ushort4*>(dst)[off] = o;
}

// ---------------- async global->LDS helper ----------------
__device__ __forceinline__ void gload_lds16(const void* g, void* l) {
  __builtin_amdgcn_global_load_lds(
      (const __attribute__((address_space(1))) unsigned int*)g,
      (__attribute__((address_space(3))) unsigned int*)l, 16, 0, 0);
}

// ============ 256xBN 8-wave pipelined GEMM (T2+T3+T4+T5) ============
// C = scale * (A . B^T) [+ bias].  A:[M][Kd] bf16 K-contig, B:[N'][Kd] bf16.
// BN=256: 8 waves 2Mx4N (wave 128x64), 4 phases/K-tile, 16 MFMA each,
//         vmcnt(4)/K-tile, LDS 128 KiB.
// BN=128: 8 waves 4Mx2N (wave 64x64), 2 phases/K-tile, 16 MFMA each,
//         vmcnt(2)/K-tile, LDS 96 KiB.
// QKV=true: N'=3072, segments of 1024 -> Q,K normal writes; V (seg 2) is
// written TRANSPOSED to vt[b][d][n] via an LDS bounce (saves vb+transpose).
template <int BN_, bool OUTF32, bool QKV>
__global__ __launch_bounds__(512) void gemm8(
    const ushort* __restrict__ Ag, const ushort* __restrict__ Bg,
    void* __restrict__ C0, void* __restrict__ C1, void* __restrict__ C2,
    const float* __restrict__ b0, const float* __restrict__ b1, const float* __restrict__ b2,
    int N, int Kd, float scale, long sA, long sB, long sC)
{
  constexpr int BM = 256;
  constexpr int BH = BN_ / 128;
  constexpr int WN = (BN_ == 256) ? 4 : 2;
  constexpr int WM = 8 / WN;
  constexpr int PWM = BM / WM;              // 128 or 64
  constexpr int RM = PWM / 16;              // 8 or 4
  constexpr int ASZ = BM * 64;              // ushorts per A buffer
  constexpr int BSZ = BN_ * 64;

  __shared__ ushort SH[2 * ASZ + 2 * BSZ];  // As dbuf | Bs dbuf (| T reuse)

  int nwg = gridDim.x * gridDim.y;
  int id = blockIdx.y * gridDim.x + blockIdx.x;
  int swz = (nwg & 7) ? id : ((id & 7) * (nwg >> 3) + (id >> 3));
  const int m0 = (swz / gridDim.x) * BM;
  const int n0 = (swz % gridDim.x) * BN_;
  const int bz = blockIdx.z;
  const char* Ab = (const char*)(Ag + (size_t)bz * sA);
  const char* Bb = (const char*)(Bg + (size_t)bz * sB);
  const int t = threadIdx.x;
  const int lane = t & 63;
  const int w = t >> 6;
  const int wm = w / WN;
  const int wn = w % WN;
  const size_t pA = (size_t)Kd * 2;
  const size_t pB = (size_t)Kd * 2;
  const int nt = Kd >> 6;

  auto stageH = [&](ushort* ldsb, const char* gb, size_t pitch) {
#pragma unroll
    for (int j = 0; j < 2; ++j) {
      int g = j * 512 + t;
      int r = g >> 3;
      int cb = ((g & 7) << 4) ^ ((r & 7) << 4);
      gload_lds16(gb + (size_t)r * pitch + cb,
                  (char*)ldsb + (size_t)((j * 512 + (t & ~63)) << 4));
    }
  };
  auto ldfrag = [&](const ushort* base, int row, int ks) -> bf16x8 {
    int L = row * 128 + ks * 64 + ((lane >> 4) << 4);
    return *(const bf16x8*)((const char*)base + (L ^ ((row & 7) << 4)));
  };

  f32x4 acc[RM][4];
#pragma unroll
  for (int i = 0; i < RM; ++i)
#pragma unroll
    for (int j = 0; j < 4; ++j) acc[i][j] = 0.f;

  bf16x8 a[4][2];
  bf16x8 bN[4][2];

#define BAR() __builtin_amdgcn_s_barrier()

  // ---- prologue ----
  stageH(SH + 2 * ASZ, Bb + (size_t)n0 * pB, pB);
  if (BH == 2) stageH(SH + 2 * ASZ + 128 * 64, Bb + (size_t)(n0 + 128) * pB, pB);
  stageH(SH, Ab + (size_t)m0 * pA, pA);
  stageH(SH + 128 * 64, Ab + (size_t)(m0 + 128) * pA, pA);
  stageH(SH + 2 * ASZ + BSZ, Bb + (size_t)n0 * pB + 128, pB);
  if (BH == 2) stageH(SH + 2 * ASZ + BSZ + 128 * 64, Bb + (size_t)(n0 + 128) * pB + 128, pB);
  if (BH == 2) asm volatile("s_waitcnt vmcnt(4)" ::: "memory");
  else         asm volatile("s_waitcnt vmcnt(2)" ::: "memory");
  BAR();

  for (int tt = 0; tt < nt; ++tt) {
    const int buf = tt & 1;
    const ushort* Ac = SH + buf * ASZ;
    const ushort* Bc = SH + 2 * ASZ + buf * BSZ;
    ushort* An = SH + (buf ^ 1) * ASZ;
    ushort* Bn = SH + 2 * ASZ + buf * BSZ;   // B(t+2) shares parity with t
    const size_t ko1 = (size_t)(tt + 1) * 128;
    const size_t ko2 = (size_t)(tt + 2) * 128;

    if constexpr (BN_ == 256) {
      // ---- P0: read A[M0] + B[N0]; stage A-half0(t+1) ----
#pragma unroll
      for (int mi = 0; mi < 4; ++mi) {
        int r = wm * 128 + mi * 16 + (lane & 15);
        a[mi][0] = ldfrag(Ac, r, 0); a[mi][1] = ldfrag(Ac, r, 1);
      }
#pragma unroll
      for (int ni = 0; ni < 2; ++ni) {
        int r = wn * 64 + ni * 16 + (lane & 15);
        bN[ni][0] = ldfrag(Bc, r, 0); bN[ni][1] = ldfrag(Bc, r, 1);
      }
      if (tt + 1 < nt) stageH(An, Ab + (size_t)m0 * pA + ko1, pA);
      BAR();
      __builtin_amdgcn_s_setprio(1);
#pragma unroll
      for (int mi = 0; mi < 4; ++mi)
#pragma unroll
        for (int ni = 0; ni < 2; ++ni) {
          acc[mi][ni] = MFMA16(a[mi][0], bN[ni][0], acc[mi][ni]);
          acc[mi][ni] = MFMA16(a[mi][1], bN[ni][1], acc[mi][ni]);
        }
      __builtin_amdgcn_s_setprio(0);
      BAR();
      // ---- P1: read B[N1]; stage A-half1(t+1) ----
#pragma unroll
      for (int ni = 0; ni < 2; ++ni) {
        int r = wn * 64 + (2 + ni) * 16 + (lane & 15);
        bN[2 + ni][0] = ldfrag(Bc, r, 0); bN[2 + ni][1] = ldfrag(Bc, r, 1);
      }
      if (tt + 1 < nt) stageH(An + 128 * 64, Ab + (size_t)(m0 + 128) * pA + ko1, pA);
      BAR();
      __builtin_amdgcn_s_setprio(1);
#pragma unroll
      for (int mi = 0; mi < 4; ++mi)
#pragma unroll
        for (int ni = 0; ni < 2; ++ni) {
          acc[mi][2 + ni] = MFMA16(a[mi][0], bN[2 + ni][0], acc[mi][2 + ni]);
          acc[mi][2 + ni] = MFMA16(a[mi][1], bN[2 + ni][1], acc[mi][2 + ni]);
        }
      __builtin_amdgcn_s_setprio(0);
      BAR();
      // ---- P2: read A[M1]; stage B-half0(t+2) ----
#pragma unroll
      for (int mi = 0; mi < 4; ++mi) {
        int r = wm * 128 + (4 + mi) * 16 + (lane & 15);
        a[mi][0] = ldfrag(Ac, r, 0); a[mi][1] = ldfrag(Ac, r, 1);
      }
      if (tt + 2 < nt) stageH(Bn, Bb + (size_t)n0 * pB + ko2, pB);
      BAR();
      __builtin_amdgcn_s_setprio(1);
#pragma unroll
      for (int mi = 0; mi < 4; ++mi)
#pragma unroll
        for (int ni = 0; ni < 2; ++ni) {
          acc[4 + mi][2 + ni] = MFMA16(a[mi][0], bN[2 + ni][0], acc[4 + mi][2 + ni]);
          acc[4 + mi][2 + ni] = MFMA16(a[mi][1], bN[2 + ni][1], acc[4 + mi][2 + ni]);
        }
      __builtin_amdgcn_s_setprio(0);
      BAR();
      // ---- P3: stage B-half1(t+2); counted vmcnt ----
      if (tt + 2 < nt) stageH(Bn + 128 * 64, Bb + (size_t)(n0 + 128) * pB + ko2, pB);
      if (tt + 2 < nt)      asm volatile("s_waitcnt vmcnt(4)" ::: "memory");
      else if (tt + 1 < nt) asm volatile("s_waitcnt vmcnt(0)" ::: "memory");
      BAR();
      __builtin_amdgcn_s_setprio(1);
#pragma unroll
      for (int mi = 0; mi < 4; ++mi)
#pragma unroll
        for (int ni = 0; ni < 2; ++ni) {
          acc[4 + mi][ni] = MFMA16(a[mi][0], bN[ni][0], acc[4 + mi][ni]);
          acc[4 + mi][ni] = MFMA16(a[mi][1], bN[ni][1], acc[4 + mi][ni]);
        }
      __builtin_amdgcn_s_setprio(0);
      BAR();
    } else {
      // ======== BN=128: 2 phases/K-tile ========
#pragma unroll
      for (int mi = 0; mi < 2; ++mi) {
        int r = wm * 64 + mi * 16 + (lane & 15);
        a[mi][0] = ldfrag(Ac, r, 0); a[mi][1] = ldfrag(Ac, r, 1);
      }
#pragma unroll
      for (int nf = 0; nf < 4; ++nf) {
        int r = wn * 64 + nf * 16 + (lane & 15);
        bN[nf][0] = ldfrag(Bc, r, 0); bN[nf][1] = ldfrag(Bc, r, 1);
      }
      if (tt + 1 < nt) stageH(An, Ab + (size_t)m0 * pA + ko1, pA);
      BAR();
      __builtin_amdgcn_s_setprio(1);
#pragma unroll
      for (int mi = 0; mi < 2; ++mi)
#pragma unroll
        for (int nf = 0; nf < 4; ++nf) {
          acc[mi][nf] = MFMA16(a[mi][0], bN[nf][0], acc[mi][nf]);
          acc[mi][nf] = MFMA16(a[mi][1], bN[nf][1], acc[mi][nf]);
        }
      __builtin_amdgcn_s_setprio(0);
      BAR();
#pragma unroll
      for (int mi = 0; mi < 2; ++mi) {
        int r = wm * 64 + (2 + mi) * 16 + (lane & 15);
        a[mi][0] = ldfrag(Ac, r, 0); a[mi][1] = ldfrag(Ac, r, 1);
      }
      if (tt + 1 < nt) stageH(An + 128 * 64, Ab + (size_t)(m0 + 128) * pA + ko1, pA);
      if (tt + 2 < nt) stageH(Bn, Bb + (size_t)n0 * pB + ko2, pB);
      if (tt + 2 < nt)      asm volatile("s_waitcnt vmcnt(2)" ::: "memory");
      else if (tt + 1 < nt) asm volatile("s_waitcnt vmcnt(0)" ::: "memory");
      BAR();
      __builtin_amdgcn_s_setprio(1);
#pragma unroll
      for (int mi = 0; mi < 2; ++mi)
#pragma unroll
        for (int nf = 0; nf < 4; ++nf) {
          acc[2 + mi][nf] = MFMA16(a[mi][0], bN[nf][0], acc[2 + mi][nf]);
          acc[2 + mi][nf] = MFMA16(a[mi][1], bN[nf][1], acc[2 + mi][nf]);
        }
      __builtin_amdgcn_s_setprio(0);
      BAR();
    }
  }
#undef BAR

  // ---- epilogue ----
  const int seg = QKV ? (n0 >> 10) : 0;
  const int n0l = QKV ? (n0 & 1023) : n0;

  if (QKV && seg == 2) {
    // V: write transposed to vt[b][d][n] via LDS bounce. T = [128][264] ushort.
    const int bb_ = m0 >> 11;
    const int nc0 = m0 & 2047;
    ushort* vtb = (ushort*)C2 + (size_t)bb_ * DIM * SEQ;
    ushort* T = SH;
#pragma unroll
    for (int h = 0; h < 2; ++h) {
      __syncthreads();
      if ((wn >> 1) == h) {
        int dl0 = (wn & 1) * 64;
#pragma unroll
        for (int nf = 0; nf < 4; ++nf) {
          int d_local = dl0 + nf * 16 + (lane & 15);
          float bvv = b2[n0l + 128 * h + d_local];
#pragma unroll
          for (int mf = 0; mf < RM; ++mf) {
            int nb = wm * PWM + mf * 16 + (lane >> 4) * 4;
            ushort4 pk;
            pk.x = f2b(acc[mf][nf][0] + bvv);
            pk.y = f2b(acc[mf][nf][1] + bvv);
            pk.z = f2b(acc[mf][nf][2] + bvv);
            pk.w = f2b(acc[mf][nf][3] + bvv);
            *(ushort4*)&T[d_local * 264 + nb] = pk;
          }
        }
      }
      __syncthreads();
      {
        int dl = t >> 2, ch = t & 3;
        ushort* dst = vtb + (size_t)(n0l + 128 * h + dl) * SEQ + nc0 + ch * 64;
#pragma unroll
        for (int i = 0; i < 8; ++i) {
          bf16x8 vv = *(const bf16x8*)&T[dl * 264 + ch * 64 + i * 8];
          *(bf16x8*)(dst + i * 8) = vv;
        }
      }
    }
    return;
  }

  const float* biasp = QKV ? (seg == 0 ? b0 : b1) : nullptr;
  void* Cp = QKV ? (seg == 0 ? C0 : C1) : C0;
  float* Cf = (float*)Cp + (size_t)bz * sC;
  ushort* Ch = (ushort*)Cp + (size_t)bz * sC;

#pragma unroll
  for (int mf = 0; mf < RM; ++mf)
#pragma unroll
    for (int nf = 0; nf < 4; ++nf) {
      int gn = n0l + wn * 64 + nf * 16 + (lane & 15);
      float bb = QKV ? biasp[gn] : 0.f;
#pragma unroll
      for (int r = 0; r < 4; ++r) {
        int gm = m0 + wm * PWM + mf * 16 + (lane >> 4) * 4 + r;
        float v = acc[mf][nf][r] * scale + bb;
        if (OUTF32) Cf[(size_t)gm * N + gn] = v;
        else        Ch[(size_t)gm * N + gn] = f2b(v);
      }
    }
}

// ---------------- row softmax, in place, bf16 ----------------
__global__ __launch_bounds__(256) void softmax_rows(ushort* __restrict__ SP) {
  const int lane = threadIdx.x & 63;
  const int w = threadIdx.x >> 6;
  const size_t row = (size_t)blockIdx.x * 4 + w;
  ushort* base = SP + row * SEQ;

  bf16x8 v[4];
  float s[32];
#pragma unroll
  for (int c = 0; c < 4; ++c) {
    v[c] = *(const bf16x8*)(base + c * 512 + lane * 8);
#pragma unroll
    for (int j = 0; j < 8; ++j) s[c * 8 + j] = b2f((ushort)v[c][j]);
  }
  float mx = s[0];
#pragma unroll
  for (int i = 1; i < 32; ++i) mx = fmaxf(mx, s[i]);
#pragma unroll
  for (int off = 1; off < 64; off <<= 1) mx = fmaxf(mx, __shfl_xor(mx, off));

  float sum = 0.f;
#pragma unroll
  for (int i = 0; i < 32; ++i) { s[i] = __expf(s[i] - mx); sum += s[i]; }
#pragma unroll
  for (int off = 1; off < 64; off <<= 1) sum += __shfl_xor(sum, off);
  float inv = 1.f / sum;

#pragma unroll
  for (int c = 0; c < 4; ++c) {
    bf16x8 o;
#pragma unroll
    for (int j = 0; j < 8; ++j) o[j] = (short)f2b(s[c * 8 + j] * inv);
    *(bf16x8*)(base + c * 512 + lane * 8) = o;
  }
}

// ---------------- launcher ----------------
extern "C" void kernel_launch(void* const* d_in, const int* in_sizes, int n_in,
                              void* d_out, int out_size, void* d_ws, size_t ws_size,
                              hipStream_t stream) {
  const float* x  = (const float*)d_in[0];
  const float* Wq = (const float*)d_in[1];
  const float* bq = (const float*)d_in[2];
  const float* Wk = (const float*)d_in[3];
  const float* bk = (const float*)d_in[4];
  const float* Wv = (const float*)d_in[5];
  const float* bv = (const float*)d_in[6];
  float* out = (float*)d_out;

  char* ws = (char*)d_ws;
  // ws layout (bytes), total 90.2 MB:
  //   [0, 16M)      free (was vb)                   \__ SP bf16 overlay [0, 32MiB)
  //   [16M, 32M)    xb   (dead after qkv gemm)      /
  //   [32M, 38.3M)  wb   (= Wq|Wk|Wv bf16, 3072 rows x 1024)
  //   [38.3M, ...)  qb | kb | vt  (16M each)
  ushort* xb = (ushort*)(ws + 16777216);
  ushort* wb = (ushort*)(ws + 33554432);
  ushort* qb = (ushort*)(ws + 39845888);
  ushort* kb = (ushort*)(ws + 56623104);
  ushort* vt = (ushort*)(ws + 73400320);
  ushort* SP = (ushort*)(ws);  // [4][2048][2048] bf16

  cvt_all<<<11264, 256, 0, stream>>>(x, Wq, Wk, Wv, xb, wb);

  // QKV: [8192 x 3072] = X . W3^T + bias -> qb/kb (normal), vt (transposed V)
  gemm8<256, false, true><<<dim3(12, 32, 1), 512, 0, stream>>>(
      xb, wb, qb, kb, vt, bq, bk, bv, DIM, DIM, 1.0f, 0, 0, 0);
  // S = Q K^T / 32 -> SP.  256 blocks.
  gemm8<256, false, false><<<dim3(8, 8, 4), 512, 0, stream>>>(
      qb, kb, SP, nullptr, nullptr, nullptr, nullptr, nullptr,
      SEQ, DIM, 0.03125f, (long)SEQ * DIM, (long)SEQ * DIM, (long)SEQ * SEQ);
  softmax_rows<<<2048, 256, 0, stream>>>(SP);
  // O = P V : A=P [2048][2048], B=Vt [1024][2048], f32 out.  256 blocks.
  gemm8<128, true, false><<<dim3(8, 8, 4), 512, 0, stream>>>(
      SP, vt, out, nullptr, nullptr, nullptr, nullptr, nullptr,
      DIM, SEQ, 1.0f, (long)SEQ * SEQ, (long)DIM * SEQ, (long)SEQ * DIM);
}

// Round 6
// 170.270 us; speedup vs baseline: 2.7870x; 1.0559x over previous
//
#include <hip/hip_runtime.h>
#include <hip/hip_bf16.h>

typedef __attribute__((ext_vector_type(4))) float f32x4;
typedef __attribute__((ext_vector_type(8))) short bf16x8;

#define MFMA16(a, b, c) __builtin_amdgcn_mfma_f32_16x16x32_bf16(a, b, c, 0, 0, 0)

constexpr int BATCH = 4;
constexpr int SEQ   = 2048;
constexpr int DIM   = 1024;

__device__ __forceinline__ ushort f2b(float f) {
  __hip_bfloat16 h = __float2bfloat16(f);
  union { __hip_bfloat16 h; ushort u; } cv; cv.h = h; return cv.u;
}
__device__ __forceinline__ float b2f(ushort u) {
  union { float f; unsigned int u; } cv; cv.u = ((unsigned int)u) << 16; return cv.f;
}

// ---------------- fused fp32 -> bf16 convert ----------------
__global__ __launch_bounds__(256) void cvt_all(
    const float* __restrict__ x, const float* __restrict__ wq,
    const float* __restrict__ wk, const float* __restrict__ wv,
    ushort* __restrict__ xb, ushort* __restrict__ wb) {
  int i = blockIdx.x * 256 + threadIdx.x;
  const float* src; ushort* dst; int off;
  if (i < 2097152) { src = x; dst = xb; off = i; }
  else {
    int j = i - 2097152;
    int s = j >> 18;
    off = j & 262143;
    src = (s == 0) ? wq : (s == 1) ? wk : wv;
    dst = wb + s * 1048576;
  }
  float4 v = reinterpret_cast<const float4*>(src)[off];
  ushort4 o;
  o.x = f2b(v.x); o.y = f2b(v.y); o.z = f2b(v.z); o.w = f2b(v.w);
  reinterpret_cast<ushort4*>(dst)[off] = o;
}

__device__ __forceinline__ void gload_lds16(const void* g, void* l) {
  __builtin_amdgcn_global_load_lds(
      (const __attribute__((address_space(1))) unsigned int*)g,
      (__attribute__((address_space(3))) unsigned int*)l, 16, 0, 0);
}

#define VWAIT(n) asm volatile("s_waitcnt vmcnt(" #n ")" ::: "memory")
#define BAR() __builtin_amdgcn_s_barrier()

// ============ 256xBN 8-wave pipelined GEMM, 1Mx8N wave mapping ============
// C = scale * (A . B^T) [+ bias].  A:[M][Kd] bf16 K-contig, B:[N'][Kd] bf16.
// Each wave owns ALL 256 rows x (BN/8)-col slice -> A-half0 consumed only in
// region A (rows 0-127), A-half1 only region B  => staged halves get >= 2
// regions of slack before first consumption; counted vmcnt never 0 mid-loop;
// 2 barriers per K-tile.
// QKV=true: N'=3072; seg 0/1 (Q,K) normal + bias; seg 2 (V) written
// TRANSPOSED to vt[b][d][n] via 2-pass LDS bounce.
template <int BN_, bool OUTF32, bool QKV>
__device__ __forceinline__ void gemm_body(
    const ushort* __restrict__ Ag, const ushort* __restrict__ Bg,
    void* __restrict__ C0, void* __restrict__ C1, void* __restrict__ C2,
    const float* __restrict__ b0, const float* __restrict__ b1, const float* __restrict__ b2,
    int N, int Kd, float scale, long sA, long sB, long sC)
{
  constexpr int NF = BN_ / 128;             // col-frags per wave (2 or 1)
  constexpr int ASZ = 256 * 64;             // ushorts per A buffer
  constexpr int BSZ = BN_ * 64;
  __shared__ ushort SH[2 * ASZ + 2 * BSZ];

  int nwg = gridDim.x * gridDim.y;
  int id = blockIdx.y * gridDim.x + blockIdx.x;
  int swz = (nwg & 7) ? id : ((id & 7) * (nwg >> 3) + (id >> 3));
  const int m0 = (swz / gridDim.x) * 256;
  const int n0 = (swz % gridDim.x) * BN_;
  const int bz = blockIdx.z;
  const char* Ab = (const char*)(Ag + (size_t)bz * sA);
  const char* Bb = (const char*)(Bg + (size_t)bz * sB);
  const int t = threadIdx.x;
  const int lane = t & 63;
  const int w = t >> 6;       // wave id = wn (1M x 8N)
  const size_t pA = (size_t)Kd * 2;
  const size_t pB = (size_t)Kd * 2;
  const int nt = Kd >> 6;

  auto stageH = [&](ushort* ldsb, const char* gb, size_t pitch) {
#pragma unroll
    for (int j = 0; j < 2; ++j) {
      int g = j * 512 + t;
      int r = g >> 3;
      int cb = ((g & 7) << 4) ^ ((r & 7) << 4);
      gload_lds16(gb + (size_t)r * pitch + cb,
                  (char*)ldsb + (size_t)((j * 512 + (t & ~63)) << 4));
    }
  };
  auto ldfrag = [&](const ushort* base, int row, int ks) -> bf16x8 {
    int L = row * 128 + ks * 64 + ((lane >> 4) << 4);
    return *(const bf16x8*)((const char*)base + (L ^ ((row & 7) << 4)));
  };

  f32x4 acc[16][NF];
#pragma unroll
  for (int i = 0; i < 16; ++i)
#pragma unroll
    for (int j = 0; j < NF; ++j) acc[i][j] = 0.f;

  bf16x8 a[4][2];
  bf16x8 b[NF][2];

  // ---- prologue: stage full tile 0, drain, barrier ----
  stageH(SH + 2 * ASZ, Bb + (size_t)n0 * pB, pB);
  if (NF == 2) stageH(SH + 2 * ASZ + 128 * 64, Bb + (size_t)(n0 + 128) * pB, pB);
  stageH(SH, Ab + (size_t)m0 * pA, pA);
  stageH(SH + 128 * 64, Ab + (size_t)(m0 + 128) * pA, pA);
  VWAIT(0);
  BAR();

  for (int tt = 0; tt < nt; ++tt) {
    const int buf = tt & 1;
    const ushort* Ac = SH + buf * ASZ;
    const ushort* Bc = SH + 2 * ASZ + buf * BSZ;
    ushort* An = SH + (buf ^ 1) * ASZ;
    ushort* Bn = SH + 2 * ASZ + (buf ^ 1) * BSZ;
    const size_t ko1 = (size_t)(tt + 1) * 128;

    // ======== region A: needs B(t) + A-half0(t) ========
    if (tt + 1 < nt) {
      stageH(Bn, Bb + (size_t)n0 * pB + ko1, pB);
      if (NF == 2) stageH(Bn + 128 * 64, Bb + (size_t)(n0 + 128) * pB + ko1, pB);
      stageH(An, Ab + (size_t)m0 * pA + ko1, pA);
      // drain through A0(t); leave newest {A1(t), B*(t+1), A0(t+1)} in flight
      if (NF == 2) VWAIT(8); else VWAIT(6);
    } else {
      VWAIT(2);
    }
    BAR();
#pragma unroll
    for (int nf = 0; nf < NF; ++nf) {
      int r = w * (16 * NF) + nf * 16 + (lane & 15);
      b[nf][0] = ldfrag(Bc, r, 0);
      b[nf][1] = ldfrag(Bc, r, 1);
    }
#pragma unroll
    for (int g = 0; g < 2; ++g) {
#pragma unroll
      for (int mi = 0; mi < 4; ++mi) {
        int r = (g * 4 + mi) * 16 + (lane & 15);
        a[mi][0] = ldfrag(Ac, r, 0);
        a[mi][1] = ldfrag(Ac, r, 1);
      }
      __builtin_amdgcn_s_setprio(1);
#pragma unroll
      for (int mi = 0; mi < 4; ++mi)
#pragma unroll
        for (int nf = 0; nf < NF; ++nf) {
          acc[g * 4 + mi][nf] = MFMA16(a[mi][0], b[nf][0], acc[g * 4 + mi][nf]);
          acc[g * 4 + mi][nf] = MFMA16(a[mi][1], b[nf][1], acc[g * 4 + mi][nf]);
        }
      __builtin_amdgcn_s_setprio(0);
    }

    // ======== region B: needs A-half1(t) ========
    if (tt + 1 < nt) {
      stageH(An + 128 * 64, Ab + (size_t)(m0 + 128) * pA + ko1, pA);
      // drain through A1(t); leave newest {B*(t+1), A0(t+1), A1(t+1)}
      if (NF == 2) VWAIT(8); else VWAIT(6);
    } else {
      VWAIT(0);
    }
    BAR();
#pragma unroll
    for (int g = 2; g < 4; ++g) {
#pragma unroll
      for (int mi = 0; mi < 4; ++mi) {
        int r = (g * 4 + mi) * 16 + (lane & 15);
        a[mi][0] = ldfrag(Ac, r, 0);
        a[mi][1] = ldfrag(Ac, r, 1);
      }
      __builtin_amdgcn_s_setprio(1);
#pragma unroll
      for (int mi = 0; mi < 4; ++mi)
#pragma unroll
        for (int nf = 0; nf < NF; ++nf) {
          acc[g * 4 + mi][nf] = MFMA16(a[mi][0], b[nf][0], acc[g * 4 + mi][nf]);
          acc[g * 4 + mi][nf] = MFMA16(a[mi][1], b[nf][1], acc[g * 4 + mi][nf]);
        }
      __builtin_amdgcn_s_setprio(0);
    }
  }

  // ---- epilogue ----
  const int seg = QKV ? (n0 >> 10) : 0;
  const int n0l = QKV ? (n0 & 1023) : n0;

  if (QKV && seg == 2) {
    // V: write transposed to vt[b][d][token] via 2-pass LDS bounce.
    __syncthreads();                         // SH reuse: all LDS reads done
    const int bb_ = m0 >> 11;
    const int tok0 = m0 & 2047;
    ushort* vtb = (ushort*)C2 + (size_t)bb_ * DIM * SEQ;
    ushort* T = SH;                          // [128][264]
#pragma unroll
    for (int nf = 0; nf < 2; ++nf) {
      {
        int rT = w * 16 + (lane & 15);
        float bvv = b2[n0l + w * 32 + nf * 16 + (lane & 15)];
#pragma unroll
        for (int mf = 0; mf < 16; ++mf) {
          ushort4 pk;
          pk.x = f2b(acc[mf][nf][0] + bvv);
          pk.y = f2b(acc[mf][nf][1] + bvv);
          pk.z = f2b(acc[mf][nf][2] + bvv);
          pk.w = f2b(acc[mf][nf][3] + bvv);
          *(ushort4*)&T[rT * 264 + mf * 16 + (lane >> 4) * 4] = pk;
        }
      }
      __syncthreads();
      {
        int rr = t >> 2, ch = t & 3;
        int d = n0l + (rr >> 4) * 32 + nf * 16 + (rr & 15);
        ushort* dst = vtb + (size_t)d * SEQ + tok0 + ch * 64;
#pragma unroll
        for (int i = 0; i < 8; ++i)
          *(bf16x8*)(dst + i * 8) = *(const bf16x8*)&T[rr * 264 + ch * 64 + i * 8];
      }
      __syncthreads();
    }
    return;
  }

  const float* biasp = QKV ? (seg == 0 ? b0 : b1) : nullptr;
  void* Cp = QKV ? (seg == 0 ? C0 : C1) : C0;
  float* Cf = (float*)Cp + (size_t)bz * sC;
  ushort* Ch = (ushort*)Cp + (size_t)bz * sC;

#pragma unroll
  for (int mf = 0; mf < 16; ++mf)
#pragma unroll
    for (int nf = 0; nf < NF; ++nf) {
      int gn = n0l + w * (16 * NF) + nf * 16 + (lane & 15);
      float bb = QKV ? biasp[gn] : 0.f;
#pragma unroll
      for (int r = 0; r < 4; ++r) {
        int gm = m0 + mf * 16 + (lane >> 4) * 4 + r;
        float v = acc[mf][nf][r] * scale + bb;
        if (OUTF32) Cf[(size_t)gm * N + gn] = v;
        else        Ch[(size_t)gm * N + gn] = f2b(v);
      }
    }
}

__global__ __launch_bounds__(512) void gemm_qkv(
    const ushort* __restrict__ Ag, const ushort* __restrict__ Bg,
    void* __restrict__ C0, void* __restrict__ C1, void* __restrict__ C2,
    const float* __restrict__ b0, const float* __restrict__ b1, const float* __restrict__ b2) {
  gemm_body<256, false, true>(Ag, Bg, C0, C1, C2, b0, b1, b2, DIM, DIM, 1.0f, 0, 0, 0);
}
__global__ __launch_bounds__(512) void gemm_s(
    const ushort* __restrict__ Ag, const ushort* __restrict__ Bg, void* __restrict__ C0) {
  gemm_body<256, false, false>(Ag, Bg, C0, nullptr, nullptr, nullptr, nullptr, nullptr,
                               SEQ, DIM, 0.03125f, (long)SEQ * DIM, (long)SEQ * DIM,
                               (long)SEQ * SEQ);
}
__global__ __launch_bounds__(512) void gemm_pv(
    const ushort* __restrict__ Ag, const ushort* __restrict__ Bg, void* __restrict__ C0) {
  gemm_body<128, true, false>(Ag, Bg, C0, nullptr, nullptr, nullptr, nullptr, nullptr,
                              DIM, SEQ, 1.0f, (long)SEQ * SEQ, (long)DIM * SEQ,
                              (long)SEQ * DIM);
}

// ---------------- row softmax, in place, bf16 ----------------
__global__ __launch_bounds__(256) void softmax_rows(ushort* __restrict__ SP) {
  const int lane = threadIdx.x & 63;
  const int w = threadIdx.x >> 6;
  const size_t row = (size_t)blockIdx.x * 4 + w;
  ushort* base = SP + row * SEQ;

  bf16x8 v[4];
  float s[32];
#pragma unroll
  for (int c = 0; c < 4; ++c) {
    v[c] = *(const bf16x8*)(base + c * 512 + lane * 8);
#pragma unroll
    for (int j = 0; j < 8; ++j) s[c * 8 + j] = b2f((ushort)v[c][j]);
  }
  float mx = s[0];
#pragma unroll
  for (int i = 1; i < 32; ++i) mx = fmaxf(mx, s[i]);
#pragma unroll
  for (int off = 1; off < 64; off <<= 1) mx = fmaxf(mx, __shfl_xor(mx, off));

  float sum = 0.f;
#pragma unroll
  for (int i = 0; i < 32; ++i) { s[i] = __expf(s[i] - mx); sum += s[i]; }
#pragma unroll
  for (int off = 1; off < 64; off <<= 1) sum += __shfl_xor(sum, off);
  float inv = 1.f / sum;

#pragma unroll
  for (int c = 0; c < 4; ++c) {
    bf16x8 o;
#pragma unroll
    for (int j = 0; j < 8; ++j) o[j] = (short)f2b(s[c * 8 + j] * inv);
    *(bf16x8*)(base + c * 512 + lane * 8) = o;
  }
}

// ---------------- launcher ----------------
extern "C" void kernel_launch(void* const* d_in, const int* in_sizes, int n_in,
                              void* d_out, int out_size, void* d_ws, size_t ws_size,
                              hipStream_t stream) {
  const float* x  = (const float*)d_in[0];
  const float* Wq = (const float*)d_in[1];
  const float* bq = (const float*)d_in[2];
  const float* Wk = (const float*)d_in[3];
  const float* bk = (const float*)d_in[4];
  const float* Wv = (const float*)d_in[5];
  const float* bv = (const float*)d_in[6];
  float* out = (float*)d_out;

  char* ws = (char*)d_ws;
  // ws layout (bytes), total 90.2 MB:
  //   [0, 32M)      SP overlay (round 1: free | xb-dead region)
  //   [16M, 32M)    xb
  //   [32M, 38.3M)  wb
  //   [38.3M, ...)  qb | kb | vt  (16M each)
  ushort* xb = (ushort*)(ws + 16777216);
  ushort* wb = (ushort*)(ws + 33554432);
  ushort* qb = (ushort*)(ws + 39845888);
  ushort* kb = (ushort*)(ws + 56623104);
  ushort* vt = (ushort*)(ws + 73400320);
  ushort* SP = (ushort*)(ws);

  cvt_all<<<11264, 256, 0, stream>>>(x, Wq, Wk, Wv, xb, wb);
  gemm_qkv<<<dim3(12, 32, 1), 512, 0, stream>>>(xb, wb, qb, kb, vt, bq, bk, bv);
  gemm_s<<<dim3(8, 8, 4), 512, 0, stream>>>(qb, kb, SP);
  softmax_rows<<<2048, 256, 0, stream>>>(SP);
  gemm_pv<<<dim3(8, 8, 4), 512, 0, stream>>>(SP, vt, out);
}

// Round 7
// 166.472 us; speedup vs baseline: 2.8505x; 1.0228x over previous
//
#include <hip/hip_runtime.h>
#include <hip/hip_bf16.h>

typedef __attribute__((ext_vector_type(4))) float f32x4;
typedef __attribute__((ext_vector_type(8))) short bf16x8;

#define MFMA16(a, b, c) __builtin_amdgcn_mfma_f32_16x16x32_bf16(a, b, c, 0, 0, 0)

constexpr int BATCH = 4;
constexpr int SEQ   = 2048;
constexpr int DIM   = 1024;

__device__ __forceinline__ ushort f2b(float f) {
  __hip_bfloat16 h = __float2bfloat16(f);
  union { __hip_bfloat16 h; ushort u; } cv; cv.h = h; return cv.u;
}

// ---------------- fused fp32 -> bf16 convert ----------------
__global__ __launch_bounds__(256) void cvt_all(
    const float* __restrict__ x, const float* __restrict__ wq,
    const float* __restrict__ wk, const float* __restrict__ wv,
    ushort* __restrict__ xb, ushort* __restrict__ wb) {
  int i = blockIdx.x * 256 + threadIdx.x;
  const float* src; ushort* dst; int off;
  if (i < 2097152) { src = x; dst = xb; off = i; }
  else {
    int j = i - 2097152;
    int s = j >> 18;
    off = j & 262143;
    src = (s == 0) ? wq : (s == 1) ? wk : wv;
    dst = wb + s * 1048576;
  }
  float4 v = reinterpret_cast<const float4*>(src)[off];
  ushort4 o;
  o.x = f2b(v.x); o.y = f2b(v.y); o.z = f2b(v.z); o.w = f2b(v.w);
  reinterpret_cast<ushort4*>(dst)[off] = o;
}

__device__ __forceinline__ void gload_lds16(const void* g, void* l) {
  __builtin_amdgcn_global_load_lds(
      (const __attribute__((address_space(1))) unsigned int*)g,
      (__attribute__((address_space(3))) unsigned int*)l, 16, 0, 0);
}

#define VWAIT(n) asm volatile("s_waitcnt vmcnt(" #n ")" ::: "memory")
#define BAR() __builtin_amdgcn_s_barrier()

// ============ 256x256 8-wave 2-region GEMM, 1Mx8N wave mapping ============
// MODE 0 (QK): C routed by seg = n0>>10 to C0/C1 with bias b0/b1, bf16 out.
// MODE 1 (S):  C = exp(scale*acc) bf16 + per-row partial sums -> lpart[b][row][8].
template <int MODE>
__device__ __forceinline__ void gemm256_body(
    const ushort* __restrict__ Ag, const ushort* __restrict__ Bg,
    void* __restrict__ C0, void* __restrict__ C1,
    const float* __restrict__ b0, const float* __restrict__ b1,
    float* __restrict__ lpart,
    int N, int Kd, float scale, long sA, long sB, long sC)
{
  constexpr int ASZ = 256 * 64;
  constexpr int BSZ = 256 * 64;
  __shared__ ushort SH[2 * ASZ + 2 * BSZ];

  int nwg = gridDim.x * gridDim.y;
  int id = blockIdx.y * gridDim.x + blockIdx.x;
  int swz = (nwg & 7) ? id : ((id & 7) * (nwg >> 3) + (id >> 3));
  const int m0 = (swz / gridDim.x) * 256;
  const int n0 = (swz % gridDim.x) * 256;
  const int bz = blockIdx.z;
  const char* Ab = (const char*)(Ag + (size_t)bz * sA);
  const char* Bb = (const char*)(Bg + (size_t)bz * sB);
  const int t = threadIdx.x;
  const int lane = t & 63;
  const int w = t >> 6;
  const size_t pA = (size_t)Kd * 2;
  const size_t pB = (size_t)Kd * 2;
  const int nt = Kd >> 6;

  auto stageH = [&](ushort* ldsb, const char* gb, size_t pitch) {
#pragma unroll
    for (int j = 0; j < 2; ++j) {
      int g = j * 512 + t;
      int r = g >> 3;
      int cb = ((g & 7) << 4) ^ ((r & 7) << 4);
      gload_lds16(gb + (size_t)r * pitch + cb,
                  (char*)ldsb + (size_t)((j * 512 + (t & ~63)) << 4));
    }
  };
  auto ldfrag = [&](const ushort* base, int row, int ks) -> bf16x8 {
    int L = row * 128 + ks * 64 + ((lane >> 4) << 4);
    return *(const bf16x8*)((const char*)base + (L ^ ((row & 7) << 4)));
  };

  f32x4 acc[16][2];
#pragma unroll
  for (int i = 0; i < 16; ++i) { acc[i][0] = 0.f; acc[i][1] = 0.f; }

  bf16x8 a[4][2];
  bf16x8 b[2][2];

  // ---- prologue ----
  stageH(SH + 2 * ASZ, Bb + (size_t)n0 * pB, pB);
  stageH(SH + 2 * ASZ + 128 * 64, Bb + (size_t)(n0 + 128) * pB, pB);
  stageH(SH, Ab + (size_t)m0 * pA, pA);
  stageH(SH + 128 * 64, Ab + (size_t)(m0 + 128) * pA, pA);
  VWAIT(0);
  BAR();

  for (int tt = 0; tt < nt; ++tt) {
    const int buf = tt & 1;
    const ushort* Ac = SH + buf * ASZ;
    const ushort* Bc = SH + 2 * ASZ + buf * BSZ;
    ushort* An = SH + (buf ^ 1) * ASZ;
    ushort* Bn = SH + 2 * ASZ + (buf ^ 1) * BSZ;
    const size_t ko1 = (size_t)(tt + 1) * 128;

    // ======== region A: needs B(t) + A-half0(t) ========
    if (tt + 1 < nt) {
      stageH(Bn, Bb + (size_t)n0 * pB + ko1, pB);
      stageH(Bn + 128 * 64, Bb + (size_t)(n0 + 128) * pB + ko1, pB);
      stageH(An, Ab + (size_t)m0 * pA + ko1, pA);
      VWAIT(8);
    } else {
      VWAIT(2);
    }
    BAR();
#pragma unroll
    for (int nf = 0; nf < 2; ++nf) {
      int r = w * 32 + nf * 16 + (lane & 15);
      b[nf][0] = ldfrag(Bc, r, 0);
      b[nf][1] = ldfrag(Bc, r, 1);
    }
#pragma unroll
    for (int g = 0; g < 2; ++g) {
#pragma unroll
      for (int mi = 0; mi < 4; ++mi) {
        int r = (g * 4 + mi) * 16 + (lane & 15);
        a[mi][0] = ldfrag(Ac, r, 0);
        a[mi][1] = ldfrag(Ac, r, 1);
      }
      __builtin_amdgcn_s_setprio(1);
#pragma unroll
      for (int mi = 0; mi < 4; ++mi)
#pragma unroll
        for (int nf = 0; nf < 2; ++nf) {
          acc[g * 4 + mi][nf] = MFMA16(a[mi][0], b[nf][0], acc[g * 4 + mi][nf]);
          acc[g * 4 + mi][nf] = MFMA16(a[mi][1], b[nf][1], acc[g * 4 + mi][nf]);
        }
      __builtin_amdgcn_s_setprio(0);
    }

    // ======== region B: needs A-half1(t) ========
    if (tt + 1 < nt) {
      stageH(An + 128 * 64, Ab + (size_t)(m0 + 128) * pA + ko1, pA);
      VWAIT(8);
    } else {
      VWAIT(0);
    }
    BAR();
#pragma unroll
    for (int g = 2; g < 4; ++g) {
#pragma unroll
      for (int mi = 0; mi < 4; ++mi) {
        int r = (g * 4 + mi) * 16 + (lane & 15);
        a[mi][0] = ldfrag(Ac, r, 0);
        a[mi][1] = ldfrag(Ac, r, 1);
      }
      __builtin_amdgcn_s_setprio(1);
#pragma unroll
      for (int mi = 0; mi < 4; ++mi)
#pragma unroll
        for (int nf = 0; nf < 2; ++nf) {
          acc[g * 4 + mi][nf] = MFMA16(a[mi][0], b[nf][0], acc[g * 4 + mi][nf]);
          acc[g * 4 + mi][nf] = MFMA16(a[mi][1], b[nf][1], acc[g * 4 + mi][nf]);
        }
      __builtin_amdgcn_s_setprio(0);
    }
  }

  if (MODE == 0) {
    // ---- QK epilogue: bias + bf16, routed by segment ----
    const int seg = n0 >> 10;
    const int n0l = n0 & 1023;
    const float* biasp = seg == 0 ? b0 : b1;
    ushort* Ch = (ushort*)(seg == 0 ? C0 : C1);
#pragma unroll
    for (int mf = 0; mf < 16; ++mf)
#pragma unroll
      for (int nf = 0; nf < 2; ++nf) {
        int gn = n0l + w * 32 + nf * 16 + (lane & 15);
        float bb = biasp[gn];
#pragma unroll
        for (int r = 0; r < 4; ++r) {
          int gm = m0 + mf * 16 + (lane >> 4) * 4 + r;
          Ch[(size_t)gm * N + gn] = f2b(acc[mf][nf][r] * scale + bb);
        }
      }
  } else {
    // ---- S epilogue: P = exp(scale*acc) bf16 + row partial sums ----
    ushort* Ch = (ushort*)C0 + (size_t)bz * sC;
    float rs[16][4];
#pragma unroll
    for (int mf = 0; mf < 16; ++mf)
#pragma unroll
      for (int r = 0; r < 4; ++r) rs[mf][r] = 0.f;
#pragma unroll
    for (int mf = 0; mf < 16; ++mf)
#pragma unroll
      for (int nf = 0; nf < 2; ++nf) {
        int gn = n0 + w * 32 + nf * 16 + (lane & 15);
#pragma unroll
        for (int r = 0; r < 4; ++r) {
          int gm = m0 + mf * 16 + (lane >> 4) * 4 + r;
          float v = __expf(acc[mf][nf][r] * scale);
          Ch[(size_t)gm * N + gn] = f2b(v);
          rs[mf][r] += v;
        }
      }
    // reduce over the 16 lanes of each quarter-group (cols within wave-slice)
#pragma unroll
    for (int mf = 0; mf < 16; ++mf)
#pragma unroll
      for (int r = 0; r < 4; ++r) {
#pragma unroll
        for (int off = 1; off < 16; off <<= 1)
          rs[mf][r] += __shfl_xor(rs[mf][r], off);
      }
    __syncthreads();                 // LDS reads all done; reuse SH
    float* Lred = (float*)SH;        // [8][256]
    f32x4 wv = 0.f;
#pragma unroll
    for (int mf = 0; mf < 16; ++mf)
      if ((lane & 15) == mf) {
        wv[0] = rs[mf][0]; wv[1] = rs[mf][1]; wv[2] = rs[mf][2]; wv[3] = rs[mf][3];
      }
    // lane k=lane&15 holds row-block mf=k: rows k*16 + (lane>>4)*4 + 0..3
    *(f32x4*)&Lred[w * 256 + (lane & 15) * 16 + (lane >> 4) * 4] = wv;
    __syncthreads();
    if (t < 256) {
      float s = 0.f;
#pragma unroll
      for (int ww = 0; ww < 8; ++ww) s += Lred[ww * 256 + t];
      lpart[((size_t)bz * SEQ + m0 + t) * 8 + (n0 >> 8)] = s;
    }
  }
}

__global__ __launch_bounds__(512) void gemm_qk(
    const ushort* __restrict__ Ag, const ushort* __restrict__ Bg,
    void* __restrict__ C0, void* __restrict__ C1,
    const float* __restrict__ b0, const float* __restrict__ b1) {
  gemm256_body<0>(Ag, Bg, C0, C1, b0, b1, nullptr, DIM, DIM, 1.0f, 0, 0, 0);
}
__global__ __launch_bounds__(512) void gemm_s(
    const ushort* __restrict__ Ag, const ushort* __restrict__ Bg,
    void* __restrict__ C0, float* __restrict__ lpart) {
  gemm256_body<1>(Ag, Bg, C0, nullptr, nullptr, nullptr, lpart,
                  SEQ, DIM, 0.03125f, (long)SEQ * DIM, (long)SEQ * DIM,
                  (long)SEQ * SEQ);
}

// ============ 256x128 8-wave single-region GEMM, 2Mx4N mapping ============
// Wave = 128 rows (its M-half) x 32 cols. Per tile: stage(t+1) 6 loads,
// vmcnt(6), BAR, reads (B 4 + A 16) + 32 MFMA, BAR.
// MODE 0 (V): out = transposed bf16 to vt[b][d][token] + bias (LDS bounce).
// MODE 1 (PV): out f32, scaled by 1/rowsum(lpart).
template <int MODE>
__device__ __forceinline__ void gemm128_body(
    const ushort* __restrict__ Ag, const ushort* __restrict__ Bg,
    void* __restrict__ Cout, const float* __restrict__ aux,
    int N, int Kd, long sA, long sB, long sC)
{
  constexpr int ASZ = 256 * 64;
  constexpr int BSZ = 128 * 64;
  __shared__ ushort SH[2 * ASZ + 2 * BSZ];   // 96 KB

  int nwg = gridDim.x * gridDim.y;
  int id = blockIdx.y * gridDim.x + blockIdx.x;
  int swz = (nwg & 7) ? id : ((id & 7) * (nwg >> 3) + (id >> 3));
  const int m0 = (swz / gridDim.x) * 256;
  const int n0 = (swz % gridDim.x) * 128;
  const int bz = blockIdx.z;
  const char* Ab = (const char*)(Ag + (size_t)bz * sA);
  const char* Bb = (const char*)(Bg + (size_t)bz * sB);
  const int t = threadIdx.x;
  const int lane = t & 63;
  const int w = t >> 6;
  const int wm = w >> 2, wn = w & 3;
  const size_t pA = (size_t)Kd * 2;
  const size_t pB = (size_t)Kd * 2;
  const int nt = Kd >> 6;

  auto stageH = [&](ushort* ldsb, const char* gb, size_t pitch) {
#pragma unroll
    for (int j = 0; j < 2; ++j) {
      int g = j * 512 + t;
      int r = g >> 3;
      int cb = ((g & 7) << 4) ^ ((r & 7) << 4);
      gload_lds16(gb + (size_t)r * pitch + cb,
                  (char*)ldsb + (size_t)((j * 512 + (t & ~63)) << 4));
    }
  };
  auto ldfrag = [&](const ushort* base, int row, int ks) -> bf16x8 {
    int L = row * 128 + ks * 64 + ((lane >> 4) << 4);
    return *(const bf16x8*)((const char*)base + (L ^ ((row & 7) << 4)));
  };

  f32x4 acc[8][2];
#pragma unroll
  for (int i = 0; i < 8; ++i) { acc[i][0] = 0.f; acc[i][1] = 0.f; }

  bf16x8 a[4][2];
  bf16x8 b[2][2];

  // ---- prologue: stage tile 0, drain ----
  stageH(SH + 2 * ASZ, Bb + (size_t)n0 * pB, pB);
  stageH(SH, Ab + (size_t)m0 * pA, pA);
  stageH(SH + 128 * 64, Ab + (size_t)(m0 + 128) * pA, pA);
  VWAIT(0);
  BAR();

  for (int tt = 0; tt < nt; ++tt) {
    const int buf = tt & 1;
    const ushort* Ac = SH + buf * ASZ;
    const ushort* Bc = SH + 2 * ASZ + buf * BSZ;
    ushort* An = SH + (buf ^ 1) * ASZ;
    ushort* Bn = SH + 2 * ASZ + (buf ^ 1) * BSZ;
    const size_t ko1 = (size_t)(tt + 1) * 128;

    if (tt + 1 < nt) {
      stageH(Bn, Bb + (size_t)n0 * pB + ko1, pB);
      stageH(An, Ab + (size_t)m0 * pA + ko1, pA);
      stageH(An + 128 * 64, Ab + (size_t)(m0 + 128) * pA + ko1, pA);
      VWAIT(6);
    } else {
      VWAIT(0);
    }
    BAR();
#pragma unroll
    for (int nf = 0; nf < 2; ++nf) {
      int r = wn * 32 + nf * 16 + (lane & 15);
      b[nf][0] = ldfrag(Bc, r, 0);
      b[nf][1] = ldfrag(Bc, r, 1);
    }
#pragma unroll
    for (int g = 0; g < 2; ++g) {
#pragma unroll
      for (int mi = 0; mi < 4; ++mi) {
        int r = wm * 128 + (g * 4 + mi) * 16 + (lane & 15);
        a[mi][0] = ldfrag(Ac, r, 0);
        a[mi][1] = ldfrag(Ac, r, 1);
      }
      __builtin_amdgcn_s_setprio(1);
#pragma unroll
      for (int mi = 0; mi < 4; ++mi)
#pragma unroll
        for (int nf = 0; nf < 2; ++nf) {
          acc[g * 4 + mi][nf] = MFMA16(a[mi][0], b[nf][0], acc[g * 4 + mi][nf]);
          acc[g * 4 + mi][nf] = MFMA16(a[mi][1], b[nf][1], acc[g * 4 + mi][nf]);
        }
      __builtin_amdgcn_s_setprio(0);
    }
    BAR();   // protects buf from next tile's stage (WAR)
  }

  if (MODE == 0) {
    // ---- V epilogue: write transposed to vt[b][d][token], +bias ----
    const int b_ = m0 >> 11;
    const int tok0 = m0 & 2047;
    ushort* vtb = (ushort*)Cout + (size_t)b_ * DIM * SEQ;
    ushort* T = SH;                       // [128][132]
    __syncthreads();
#pragma unroll
    for (int h = 0; h < 2; ++h) {
      if (wm == h) {
#pragma unroll
        for (int nf = 0; nf < 2; ++nf) {
          int d_local = wn * 32 + nf * 16 + (lane & 15);
          float bvv = aux[n0 + d_local];
#pragma unroll
          for (int mf = 0; mf < 8; ++mf) {
            ushort4 pk;
            pk.x = f2b(acc[mf][nf][0] + bvv);
            pk.y = f2b(acc[mf][nf][1] + bvv);
            pk.z = f2b(acc[mf][nf][2] + bvv);
            pk.w = f2b(acc[mf][nf][3] + bvv);
            *(ushort4*)&T[d_local * 132 + mf * 16 + (lane >> 4) * 4] = pk;
          }
        }
      }
      __syncthreads();
      {
        int rr = t >> 2, ch = t & 3;
        ushort* dst = vtb + (size_t)(n0 + rr) * SEQ + tok0 + h * 128 + ch * 32;
#pragma unroll
        for (int i = 0; i < 4; ++i)
          *(bf16x8*)(dst + i * 8) = *(const bf16x8*)&T[rr * 132 + ch * 32 + i * 8];
      }
      __syncthreads();
    }
  } else {
    // ---- PV epilogue: O = acc / rowsum(lpart), f32 out ----
    const float* lp = aux + (size_t)bz * SEQ * 8;
    float* Cf = (float*)Cout + (size_t)bz * sC;
#pragma unroll
    for (int mf = 0; mf < 8; ++mf) {
      int row0 = m0 + wm * 128 + mf * 16 + (lane >> 4) * 4;
      float inv[4];
#pragma unroll
      for (int r = 0; r < 4; ++r) {
        const f32x4* q = (const f32x4*)(lp + (size_t)(row0 + r) * 8);
        f32x4 u = q[0] + q[1];
        inv[r] = 1.f / (u[0] + u[1] + u[2] + u[3]);
      }
#pragma unroll
      for (int nf = 0; nf < 2; ++nf) {
        int gn = n0 + wn * 32 + nf * 16 + (lane & 15);
#pragma unroll
        for (int r = 0; r < 4; ++r)
          Cf[(size_t)(row0 + r) * N + gn] = acc[mf][nf][r] * inv[r];
      }
    }
  }
}

__global__ __launch_bounds__(512) void gemm_v(
    const ushort* __restrict__ Ag, const ushort* __restrict__ Bg,
    void* __restrict__ Cout, const float* __restrict__ bv) {
  gemm128_body<0>(Ag, Bg, Cout, bv, DIM, DIM, 0, 0, 0);
}
__global__ __launch_bounds__(512) void gemm_pv(
    const ushort* __restrict__ Ag, const ushort* __restrict__ Bg,
    void* __restrict__ Cout, const float* __restrict__ lpart) {
  gemm128_body<1>(Ag, Bg, Cout, lpart, DIM, SEQ,
                  (long)SEQ * SEQ, (long)DIM * SEQ, (long)SEQ * DIM);
}

// ---------------- launcher ----------------
extern "C" void kernel_launch(void* const* d_in, const int* in_sizes, int n_in,
                              void* d_out, int out_size, void* d_ws, size_t ws_size,
                              hipStream_t stream) {
  const float* x  = (const float*)d_in[0];
  const float* Wq = (const float*)d_in[1];
  const float* bq = (const float*)d_in[2];
  const float* Wk = (const float*)d_in[3];
  const float* bk = (const float*)d_in[4];
  const float* Wv = (const float*)d_in[5];
  const float* bv = (const float*)d_in[6];
  float* out = (float*)d_out;

  char* ws = (char*)d_ws;
  // ws layout (bytes), total 90.2 MB:
  //   [0, 32M)      SP  [4][2048][2048] bf16   (written by gemm_s; overlays
  //                 the region where xb sits at [16M,32M) — xb dead by then)
  //   [32M, 38.3M)  wb  [3072][1024] bf16 (dead after gemm_v) / lpart overlay
  //   [38.3M, ...)  qb | kb | vt  (16M each)
  ushort* xb = (ushort*)(ws + 16777216);
  ushort* wb = (ushort*)(ws + 33554432);
  ushort* qb = (ushort*)(ws + 39845888);
  ushort* kb = (ushort*)(ws + 56623104);
  ushort* vt = (ushort*)(ws + 73400320);
  ushort* SP = (ushort*)(ws);
  float* lpart = (float*)(ws + 33554432);  // [4][2048][8] f32, overlays dead wb

  cvt_all<<<11264, 256, 0, stream>>>(x, Wq, Wk, Wv, xb, wb);
  // Q,K: [8192 x 2048] = X . [Wq;Wk]^T + bias.  256 blocks = 1 clean round.
  gemm_qk<<<dim3(8, 32, 1), 512, 0, stream>>>(xb, wb, qb, kb, bq, bk);
  // V: [8192 x 1024] = X . Wv^T + bias, written transposed to vt.  256 blocks.
  gemm_v<<<dim3(8, 32, 1), 512, 0, stream>>>(xb, wb + 2097152, vt, bv);
  // P = exp(Q K^T / 32) -> SP (+ row partial sums -> lpart).  256 blocks.
  gemm_s<<<dim3(8, 8, 4), 512, 0, stream>>>(qb, kb, SP, lpart);
  // O = (P V) / rowsum.  256 blocks.
  gemm_pv<<<dim3(8, 8, 4), 512, 0, stream>>>(SP, vt, out, lpart);
}